// Round 3
// baseline (2085.470 us; speedup 1.0000x reference)
//
#include <hip/hip_runtime.h>
#include <math.h>
#include <stdint.h>

// Problem constants
#define B_ 512
#define D_ 1024
#define H_ 1024
#define T_ 48
#define NG 4096      // 4*H gate columns

typedef _Float16 half8 __attribute__((ext_vector_type(8)));
typedef float f32x4 __attribute__((ext_vector_type(4)));

// Async global->LDS, 16B per lane. LDS dest must be wave-uniform base; HW adds lane*16.
// Global source IS per-lane.
__device__ __forceinline__ void cp16(const void* g, void* l) {
  __builtin_amdgcn_global_load_lds(
      (__attribute__((address_space(1))) const unsigned int*)(uintptr_t)g,
      (__attribute__((address_space(3))) unsigned int*)(uintptr_t)l, 16, 0, 0);
}

__device__ __forceinline__ float sigmoidf_(float x) { return 1.0f / (1.0f + expf(-x)); }

// ---------------------------------------------------------------------------
// Prep: Wx1[j][k]=W_ih[j][k] (k<1024) f16; Wp[j][k]=W_ih[j][1024+k] f16
// ---------------------------------------------------------------------------
__global__ void prep_w(const float* __restrict__ W_ih,
                       _Float16* __restrict__ Wx1, _Float16* __restrict__ Wp) {
  int idx = blockIdx.x * 256 + threadIdx.x;  // < 8388608
  const int n1 = NG * H_;  // 4,194,304
  if (idx < n1) {
    int j = idx >> 10, k = idx & 1023;
    Wx1[idx] = (_Float16)W_ih[j * 2048 + k];
  } else {
    int i3 = idx - n1;
    int j = i3 >> 10, k = i3 & 1023;
    Wp[i3] = (_Float16)W_ih[j * 2048 + 1024 + k];
  }
}

// ---------------------------------------------------------------------------
// Whh -> MFMA B-fragment order, per column-block cb (16 hidden cols).
// Fragment f = ((cb*4 + n)*32 + kc)*64 + lane holds half8:
//   B[row = n*1024 + cb*16 + (lane&15)][k = kc*32 + (lane>>4)*8 .. +8]
// so ds_read_b128 at (frag_base + lane*16) is the exact 16x16x32 B operand,
// consecutive lanes -> consecutive 16B -> conflict-free.
// ---------------------------------------------------------------------------
__global__ void prep_wfrag(const float* __restrict__ W_hh, _Float16* __restrict__ Wf) {
  int f = blockIdx.x * 256 + threadIdx.x;  // < 524288
  int cb = f >> 13;
  int rem = f & 8191;
  int n = rem >> 11;
  int kc = (rem >> 6) & 31;
  int lane = rem & 63;
  int l16 = lane & 15, quad = lane >> 4;
  const float* s = W_hh + (size_t)(n * 1024 + cb * 16 + l16) * 1024 + kc * 32 + quad * 8;
  half8 v;
#pragma unroll
  for (int i = 0; i < 8; ++i) v[i] = (_Float16)s[i];
  *(half8*)(Wf + (size_t)f * 8) = v;
}

// ---------------------------------------------------------------------------
// Pool: pooled[b][d] = sum_t mask(t,b)*dh[t][b][d] / sum_t mask(t,b); also dh->f16 (t>=1)
// ---------------------------------------------------------------------------
__global__ void pool_conv(const float* __restrict__ dh, const int* __restrict__ caps,
                          _Float16* __restrict__ dh16, _Float16* __restrict__ pooled16) {
  int tid = blockIdx.x * 256 + threadIdx.x;  // b*1024 + d, < 524288
  int b = tid >> 10;
  float sum = 0.0f, cnt = 0.0f;
  for (int t = 0; t < T_; ++t) {
    int cap = caps[t * B_ + b];
    float v = dh[(size_t)t * (B_ * D_) + tid];
    if (cap != 0 && cap != 2) { sum += v; cnt += 1.0f; }
    if (t >= 1) dh16[(size_t)t * (B_ * D_) + tid] = (_Float16)v;
  }
  pooled16[tid] = (_Float16)(sum / cnt);
}

// ---------------------------------------------------------------------------
// Init: feats[:,0,:]=0, grid-barrier state = 0 (re-zeroed every replay).
// ---------------------------------------------------------------------------
__global__ void init_zero(float* __restrict__ out, unsigned* __restrict__ bar) {
  int tid = blockIdx.x * 256 + threadIdx.x;  // < 524288
  int b = tid >> 10, d = tid & 1023;
  out[(size_t)b * (T_ * H_) + d] = 0.0f;
  if (tid < 2) bar[tid] = 0u;
}

// ---------------------------------------------------------------------------
// Xc[b][n] = sum_k pooled[b][k]*Wp[n][k] + b_ih[n] + b_hh[n]   (f32, B x 4096)
// ---------------------------------------------------------------------------
__global__ __launch_bounds__(256) void gemm_pool(
    const _Float16* __restrict__ A, const _Float16* __restrict__ Wp,
    const float* __restrict__ b_ih, const float* __restrict__ b_hh,
    float* __restrict__ Xc) {
  __shared__ __align__(16) _Float16 sA[64 * 32];
  __shared__ __align__(16) _Float16 sB[128 * 32];
  const int tid = threadIdx.x;
  const int wave = tid >> 6, lane = tid & 63;
  const int quad = lane >> 4, l16 = lane & 15;
  const int wm = wave & 1, wn = wave >> 1;
  const int n0 = blockIdx.x * 128;
  const int b0 = blockIdx.y * 64;
  const int rS = tid >> 2, cS = tid & 3;

  f32x4 acc[2][4] = {};
  for (int k0 = 0; k0 < 1024; k0 += 32) {
    cp16(A + (size_t)(b0 + rS) * 1024 + k0 + cS * 8, sA + wave * 512);
    cp16(Wp + (size_t)(n0 + rS) * 1024 + k0 + cS * 8, sB + wave * 512);
    cp16(Wp + (size_t)(n0 + 64 + rS) * 1024 + k0 + cS * 8, sB + 2048 + wave * 512);
    __syncthreads();
    half8 a[2], bfr[4];
#pragma unroll
    for (int m = 0; m < 2; ++m)
      a[m] = *(const half8*)(sA + (wm * 32 + m * 16 + l16) * 32 + quad * 8);
#pragma unroll
    for (int n = 0; n < 4; ++n)
      bfr[n] = *(const half8*)(sB + (wn * 64 + n * 16 + l16) * 32 + quad * 8);
#pragma unroll
    for (int m = 0; m < 2; ++m)
#pragma unroll
      for (int n = 0; n < 4; ++n)
        acc[m][n] = __builtin_amdgcn_mfma_f32_16x16x32_f16(a[m], bfr[n], acc[m][n], 0, 0, 0);
    __syncthreads();
  }
#pragma unroll
  for (int m = 0; m < 2; ++m) {
#pragma unroll
    for (int n = 0; n < 4; ++n) {
      int nn = n0 + wn * 64 + n * 16 + l16;
      float bias = b_ih[nn] + b_hh[nn];
#pragma unroll
      for (int r = 0; r < 4; ++r) {
        int bb = b0 + wm * 32 + m * 16 + quad * 4 + r;
        Xc[(size_t)bb * NG + nn] = acc[m][n][r] + bias;
      }
    }
  }
}

// ---------------------------------------------------------------------------
// Big input-projection GEMM (hoisted out of the recurrence):
//   Xall[r][n] (f16) = sum_k A[r][k]*Wx1[n][k] + Xc[r&511][n]
// M=24064, N=4096, K=1024. 128x128 tile, 2-phase double-buffered LDS.
// (Unchanged this round; 8-phase port is the next candidate.)
// ---------------------------------------------------------------------------
__global__ __launch_bounds__(256) void gemm_x(
    const _Float16* __restrict__ A, const _Float16* __restrict__ Bw,
    const float* __restrict__ Xc, _Float16* __restrict__ Xall) {
  __shared__ __align__(16) _Float16 sA[2][128 * 32];
  __shared__ __align__(16) _Float16 sB[2][128 * 32];
  const int tid = threadIdx.x;
  const int wave = tid >> 6, lane = tid & 63;
  const int quad = lane >> 4, l16 = lane & 15;
  const int wm = wave & 1, wn = wave >> 1;
  const int n0 = blockIdx.x * 128;
  const int m0 = blockIdx.y * 128;
  const int rS = tid >> 2, cS = tid & 3;

  const _Float16* aR0 = A + (size_t)(m0 + rS) * 1024 + cS * 8;
  const _Float16* aR1 = A + (size_t)(m0 + 64 + rS) * 1024 + cS * 8;
  const _Float16* bR0 = Bw + (size_t)(n0 + rS) * 1024 + cS * 8;
  const _Float16* bR1 = Bw + (size_t)(n0 + 64 + rS) * 1024 + cS * 8;

  f32x4 acc[4][4] = {};

  auto stage = [&](int buf, int k0) {
    cp16(aR0 + k0, &sA[buf][wave * 512]);
    cp16(aR1 + k0, &sA[buf][2048 + wave * 512]);
    cp16(bR0 + k0, &sB[buf][wave * 512]);
    cp16(bR1 + k0, &sB[buf][2048 + wave * 512]);
  };
  auto compute = [&](int cur) {
    half8 a[4], b[4];
#pragma unroll
    for (int m = 0; m < 4; ++m)
      a[m] = *(const half8*)&sA[cur][(wm * 64 + m * 16 + l16) * 32 + quad * 8];
#pragma unroll
    for (int n = 0; n < 4; ++n)
      b[n] = *(const half8*)&sB[cur][(wn * 64 + n * 16 + l16) * 32 + quad * 8];
#pragma unroll
    for (int m = 0; m < 4; ++m)
#pragma unroll
      for (int n = 0; n < 4; ++n)
        acc[m][n] = __builtin_amdgcn_mfma_f32_16x16x32_f16(a[m], b[n], acc[m][n], 0, 0, 0);
  };

  stage(0, 0);
  __syncthreads();
  for (int it = 0; it < 31; ++it) {
    const int cur = it & 1;
    stage(cur ^ 1, (it + 1) * 32);
    compute(cur);
    __syncthreads();
  }
  compute(1);  // it=31

#pragma unroll
  for (int m = 0; m < 4; ++m) {
#pragma unroll
    for (int n = 0; n < 4; ++n) {
      const int col = n0 + wn * 64 + n * 16 + l16;
#pragma unroll
      for (int r = 0; r < 4; ++r) {
        const int row = m0 + wm * 64 + m * 16 + quad * 4 + r;
        Xall[(size_t)row * NG + col] =
            (_Float16)(acc[m][n][r] + Xc[(size_t)(row & 511) * NG + col]);
      }
    }
  }
}

// ---------------------------------------------------------------------------
// PERSISTENT recurrent kernel: one launch for all 47 steps.
// 256 blocks (1/CU via 128KiB LDS) x 256 threads (4 waves).
// Block (cb,bb): 16 hidden cols (all 4 gates) x 128 batches.
// Weights: LDS-resident fragment array (loaded once, conflict-free reads).
// A (h_prev): direct global->reg, 2-chunk pipeline, NO barriers in K-loop.
// c: registers across all steps. h: fresh slab per step (no stale-L2 hazard);
// per-block agent fence (L2 writeback) + atomic grid barrier between steps.
// ---------------------------------------------------------------------------
__global__ __launch_bounds__(256, 1) void lstm_all(
    const _Float16* __restrict__ Wf, const _Float16* __restrict__ Xall,
    _Float16* __restrict__ hs, float* __restrict__ out,
    unsigned* __restrict__ bar) {
  __shared__ __align__(16) _Float16 wlds[65536];  // 128 KiB
  const int tid = threadIdx.x;
  const int wave = tid >> 6, lane = tid & 63;
  const int quad = lane >> 4, l16 = lane & 15;
  const int cb = blockIdx.x >> 2, bb = blockIdx.x & 3;
  const int col = cb * 16 + l16;

  // --- weight fragments -> LDS, once (fully coalesced, linear dest)
  {
    const _Float16* src = Wf + (size_t)cb * 65536;
#pragma unroll
    for (int i = 0; i < 32; ++i)
      cp16(src + (size_t)(i * 256 + wave * 64 + lane) * 8,
           wlds + (i * 256 + wave * 64) * 8);
  }
  __syncthreads();

  float cc[2][4] = {{0.f, 0.f, 0.f, 0.f}, {0.f, 0.f, 0.f, 0.f}};

  for (int t = 1; t < T_; ++t) {
    // --- Xall prefetch (T14: issue before K-loop, consume in epilogue)
    _Float16 xh[2][4][4];
    {
      const _Float16* xb =
          Xall + ((size_t)(t - 1) * 512 + bb * 128 + wave * 32) * NG + col;
#pragma unroll
      for (int m = 0; m < 2; ++m)
#pragma unroll
        for (int r = 0; r < 4; ++r) {
          const _Float16* xr = xb + (size_t)(m * 16 + quad * 4 + r) * NG;
#pragma unroll
          for (int n = 0; n < 4; ++n) xh[m][n][r] = xr[n * 1024];
        }
    }

    f32x4 acc[2][4] = {};
    if (t > 1) {
      const _Float16* hp = hs + (size_t)(t - 1) * 524288;
      const _Float16* aB0 = hp + (size_t)(bb * 128 + wave * 32 + l16) * 1024 + quad * 8;
      const _Float16* aB1 = aB0 + 16 * 1024;
      half8 abuf[2][2][2];  // [parity][m][kk] — all indices compile-time (full unroll)
#define LOADA(P, CH)                                      \
  do {                                                    \
    abuf[P][0][0] = *(const half8*)(aB0 + (CH) * 64);      \
    abuf[P][0][1] = *(const half8*)(aB0 + (CH) * 64 + 32); \
    abuf[P][1][0] = *(const half8*)(aB1 + (CH) * 64);      \
    abuf[P][1][1] = *(const half8*)(aB1 + (CH) * 64 + 32); \
  } while (0)
      LOADA(0, 0);
      LOADA(1, 1);
#pragma unroll
      for (int ch = 0; ch < 16; ++ch) {
        half8 bf[2][4];
#pragma unroll
        for (int kk = 0; kk < 2; ++kk)
#pragma unroll
          for (int n = 0; n < 4; ++n)
            bf[kk][n] =
                *(const half8*)&wlds[(size_t)((n * 32 + ch * 2 + kk) * 64 + lane) * 8];
        const int p = ch & 1;
#pragma unroll
        for (int kk = 0; kk < 2; ++kk)
#pragma unroll
          for (int m = 0; m < 2; ++m)
#pragma unroll
            for (int n = 0; n < 4; ++n)
              acc[m][n] = __builtin_amdgcn_mfma_f32_16x16x32_f16(
                  abuf[p][m][kk], bf[kk][n], acc[m][n], 0, 0, 0);
        if (ch < 14) LOADA(p, ch + 2);
      }
#undef LOADA
    }

    // --- epilogue: gates -> c (regs) -> h slab t + out
    _Float16* hw = hs + (size_t)t * 524288;
#pragma unroll
    for (int m = 0; m < 2; ++m)
#pragma unroll
      for (int r = 0; r < 4; ++r) {
        int b = bb * 128 + wave * 32 + m * 16 + quad * 4 + r;
        float iv = acc[m][0][r] + (float)xh[m][0][r];
        float fv = acc[m][1][r] + (float)xh[m][1][r];
        float gv = acc[m][2][r] + (float)xh[m][2][r];
        float ov = acc[m][3][r] + (float)xh[m][3][r];
        float ig = sigmoidf_(iv), fg = sigmoidf_(fv), og = sigmoidf_(ov);
        float gg = tanhf(gv);
        float cn = fg * cc[m][r] + ig * gg;
        cc[m][r] = cn;
        float hv = og * tanhf(cn);
        hw[(size_t)b * 1024 + col] = (_Float16)hv;
        out[(size_t)b * (T_ * H_) + (size_t)t * H_ + col] = hv;
      }

    // --- grid barrier (sense via generation counter), agent-scope release
    __syncthreads();  // drains this block's stores (vmcnt before s_barrier)
    if (tid == 0) {
      __threadfence();  // agent fence: L2 writeback -> h visible cross-XCD
      unsigned arrived = __hip_atomic_fetch_add(&bar[0], 1u, __ATOMIC_ACQ_REL,
                                                __HIP_MEMORY_SCOPE_AGENT);
      if (arrived == 255u) {
        __hip_atomic_store(&bar[0], 0u, __ATOMIC_RELAXED, __HIP_MEMORY_SCOPE_AGENT);
        __hip_atomic_store(&bar[1], (unsigned)t, __ATOMIC_RELEASE,
                           __HIP_MEMORY_SCOPE_AGENT);
      } else {
        while (__hip_atomic_load(&bar[1], __ATOMIC_ACQUIRE,
                                 __HIP_MEMORY_SCOPE_AGENT) < (unsigned)t)
          __builtin_amdgcn_s_sleep(8);
      }
    }
    __syncthreads();
  }
}

// ---------------------------------------------------------------------------
extern "C" void kernel_launch(void* const* d_in, const int* in_sizes, int n_in,
                              void* d_out, int out_size, void* d_ws, size_t ws_size,
                              hipStream_t stream) {
  (void)in_sizes; (void)n_in; (void)out_size; (void)ws_size;
  const float* dh   = (const float*)d_in[0];
  // d_in[1] ("outputs") is unused by the reference
  const int*   caps = (const int*)d_in[2];
  const float* W_ih = (const float*)d_in[3];
  const float* W_hh = (const float*)d_in[4];
  const float* b_ih = (const float*)d_in[5];
  const float* b_hh = (const float*)d_in[6];
  float* out = (float*)d_out;

  // Workspace layout (~286 MB, unchanged total):
  char* ws = (char*)d_ws;
  _Float16* Wx116 = (_Float16*)(ws);                 //   8,388,608
  _Float16* Wfrag = (_Float16*)(ws + 8388608);       //   8,388,608 (fragment-ordered Whh)
  _Float16* Wp    = (_Float16*)(ws + 16777216);      //   8,388,608
  _Float16* dh16  = (_Float16*)(ws + 25165824);      //  50,331,648 (REUSED as h slabs after gemm_x)
  _Float16* pld16 = (_Float16*)(ws + 75497472);      //   1,048,576
  float*    Xc    = (float*)   (ws + 76546048);      //   8,388,608
  _Float16* Xall  = (_Float16*)(ws + 84934656);      // 197,132,288 (47*512*4096 f16)
  unsigned* bar   = (unsigned*)(ws + 282066944);     //   8 B barrier state

  prep_w<<<32768, 256, 0, stream>>>(W_ih, Wx116, Wp);
  prep_wfrag<<<2048, 256, 0, stream>>>(W_hh, Wfrag);
  pool_conv<<<2048, 256, 0, stream>>>(dh, caps, dh16, pld16);
  init_zero<<<2048, 256, 0, stream>>>(out, bar);
  gemm_pool<<<dim3(32, 8), 256, 0, stream>>>(pld16, Wp, b_ih, b_hh, Xc);
  // A = dh16 rows from t=1 onward: dh16 + 512*1024 elements, [24064 x 1024] f16
  gemm_x<<<dim3(32, 188), 256, 0, stream>>>(dh16 + 524288, Wx116, Xc, Xall);
  // h slab t (t=1..47) lives at dh16-region byte offset t*1MB (dh16 dead after gemm_x)
  lstm_all<<<256, 256, 0, stream>>>(Wfrag, Xall, dh16, out, bar);
}

// Round 4
// 1744.342 us; speedup vs baseline: 1.1956x; 1.1956x over previous
//
#include <hip/hip_runtime.h>
#include <math.h>
#include <stdint.h>

// Problem constants
#define B_ 512
#define D_ 1024
#define H_ 1024
#define T_ 48
#define NG 4096      // 4*H gate columns

typedef _Float16 half8 __attribute__((ext_vector_type(8)));
typedef float f32x4 __attribute__((ext_vector_type(4)));

// Async global->LDS, 16B per lane. LDS dest must be wave-uniform base; HW adds lane*16.
// Global source IS per-lane.
__device__ __forceinline__ void cp16(const void* g, void* l) {
  __builtin_amdgcn_global_load_lds(
      (__attribute__((address_space(1))) const unsigned int*)(uintptr_t)g,
      (__attribute__((address_space(3))) unsigned int*)(uintptr_t)l, 16, 0, 0);
}

__device__ __forceinline__ float sigmoidf_(float x) { return 1.0f / (1.0f + expf(-x)); }

// ---------------------------------------------------------------------------
// Prep: Wx1[j][k]=W_ih[j][k] (k<1024) f16; Wp[j][k]=W_ih[j][1024+k] f16
// ---------------------------------------------------------------------------
__global__ void prep_w(const float* __restrict__ W_ih,
                       _Float16* __restrict__ Wx1, _Float16* __restrict__ Wp) {
  int idx = blockIdx.x * 256 + threadIdx.x;  // < 8388608
  const int n1 = NG * H_;  // 4,194,304
  if (idx < n1) {
    int j = idx >> 10, k = idx & 1023;
    Wx1[idx] = (_Float16)W_ih[j * 2048 + k];
  } else {
    int i3 = idx - n1;
    int j = i3 >> 10, k = i3 & 1023;
    Wp[i3] = (_Float16)W_ih[j * 2048 + 1024 + k];
  }
}

// ---------------------------------------------------------------------------
// Whh -> MFMA B-fragment order, per column-block cb (16 hidden cols).
// Fragment f = ((cb*4 + n)*32 + kc)*64 + lane holds half8:
//   B[row = n*1024 + cb*16 + (lane&15)][k = kc*32 + (lane>>4)*8 .. +8]
// so ds_read_b128 at (frag_base + lane*16) is the exact 16x16x32 B operand,
// consecutive lanes -> consecutive 16B -> conflict-free.
// ---------------------------------------------------------------------------
__global__ void prep_wfrag(const float* __restrict__ W_hh, _Float16* __restrict__ Wf) {
  int f = blockIdx.x * 256 + threadIdx.x;  // < 524288
  int cb = f >> 13;
  int rem = f & 8191;
  int n = rem >> 11;
  int kc = (rem >> 6) & 31;
  int lane = rem & 63;
  int l16 = lane & 15, quad = lane >> 4;
  const float* s = W_hh + (size_t)(n * 1024 + cb * 16 + l16) * 1024 + kc * 32 + quad * 8;
  half8 v;
#pragma unroll
  for (int i = 0; i < 8; ++i) v[i] = (_Float16)s[i];
  *(half8*)(Wf + (size_t)f * 8) = v;
}

// ---------------------------------------------------------------------------
// Pool: pooled[b][d] = sum_t mask(t,b)*dh[t][b][d] / sum_t mask(t,b); also dh->f16 (t>=1)
// ---------------------------------------------------------------------------
__global__ void pool_conv(const float* __restrict__ dh, const int* __restrict__ caps,
                          _Float16* __restrict__ dh16, _Float16* __restrict__ pooled16) {
  int tid = blockIdx.x * 256 + threadIdx.x;  // b*1024 + d, < 524288
  int b = tid >> 10;
  float sum = 0.0f, cnt = 0.0f;
  for (int t = 0; t < T_; ++t) {
    int cap = caps[t * B_ + b];
    float v = dh[(size_t)t * (B_ * D_) + tid];
    if (cap != 0 && cap != 2) { sum += v; cnt += 1.0f; }
    if (t >= 1) dh16[(size_t)t * (B_ * D_) + tid] = (_Float16)v;
  }
  pooled16[tid] = (_Float16)(sum / cnt);
}

// ---------------------------------------------------------------------------
// Init: feats[:,0,:]=0, barrier flags = 0 (re-zeroed every replay).
// Flags: 4 groups x 64 blocks, padded to 16 dwords (64B) each -> 4096 dwords.
// ---------------------------------------------------------------------------
__global__ void init_zero(float* __restrict__ out, unsigned* __restrict__ bar) {
  int tid = blockIdx.x * 256 + threadIdx.x;  // < 524288
  int b = tid >> 10, d = tid & 1023;
  out[(size_t)b * (T_ * H_) + d] = 0.0f;
  if (tid < 4096) bar[tid] = 0u;
}

// ---------------------------------------------------------------------------
// Xc[b][n] = sum_k pooled[b][k]*Wp[n][k] + b_ih[n] + b_hh[n]   (f32, B x 4096)
// ---------------------------------------------------------------------------
__global__ __launch_bounds__(256) void gemm_pool(
    const _Float16* __restrict__ A, const _Float16* __restrict__ Wp,
    const float* __restrict__ b_ih, const float* __restrict__ b_hh,
    float* __restrict__ Xc) {
  __shared__ __align__(16) _Float16 sA[64 * 32];
  __shared__ __align__(16) _Float16 sB[128 * 32];
  const int tid = threadIdx.x;
  const int wave = tid >> 6, lane = tid & 63;
  const int quad = lane >> 4, l16 = lane & 15;
  const int wm = wave & 1, wn = wave >> 1;
  const int n0 = blockIdx.x * 128;
  const int b0 = blockIdx.y * 64;
  const int rS = tid >> 2, cS = tid & 3;

  f32x4 acc[2][4] = {};
  for (int k0 = 0; k0 < 1024; k0 += 32) {
    cp16(A + (size_t)(b0 + rS) * 1024 + k0 + cS * 8, sA + wave * 512);
    cp16(Wp + (size_t)(n0 + rS) * 1024 + k0 + cS * 8, sB + wave * 512);
    cp16(Wp + (size_t)(n0 + 64 + rS) * 1024 + k0 + cS * 8, sB + 2048 + wave * 512);
    __syncthreads();
    half8 a[2], bfr[4];
#pragma unroll
    for (int m = 0; m < 2; ++m)
      a[m] = *(const half8*)(sA + (wm * 32 + m * 16 + l16) * 32 + quad * 8);
#pragma unroll
    for (int n = 0; n < 4; ++n)
      bfr[n] = *(const half8*)(sB + (wn * 64 + n * 16 + l16) * 32 + quad * 8);
#pragma unroll
    for (int m = 0; m < 2; ++m)
#pragma unroll
      for (int n = 0; n < 4; ++n)
        acc[m][n] = __builtin_amdgcn_mfma_f32_16x16x32_f16(a[m], bfr[n], acc[m][n], 0, 0, 0);
    __syncthreads();
  }
#pragma unroll
  for (int m = 0; m < 2; ++m) {
#pragma unroll
    for (int n = 0; n < 4; ++n) {
      int nn = n0 + wn * 64 + n * 16 + l16;
      float bias = b_ih[nn] + b_hh[nn];
#pragma unroll
      for (int r = 0; r < 4; ++r) {
        int bb = b0 + wm * 32 + m * 16 + quad * 4 + r;
        Xc[(size_t)bb * NG + nn] = acc[m][n][r] + bias;
      }
    }
  }
}

// ---------------------------------------------------------------------------
// Big input-projection GEMM: Xall[r][n] (f16) = sum_k A[r][k]*Wx1[n][k] + Xc[r&511][n]
// M=24064, N=4096, K=1024. 128x128 tile, 2-phase double-buffered LDS.
// NEW: both-sides XOR swizzle (chunk ^= (row>>1)&3): linear LDS dest (cp16
// requirement) + pre-swizzled global source + swizzled ds_read. The old
// quad*8 reads at row-stride-64B were a measured 2.46e7-conflict pattern.
// ---------------------------------------------------------------------------
__global__ __launch_bounds__(256) void gemm_x(
    const _Float16* __restrict__ A, const _Float16* __restrict__ Bw,
    const float* __restrict__ Xc, _Float16* __restrict__ Xall) {
  __shared__ __align__(16) _Float16 sA[2][128 * 32];
  __shared__ __align__(16) _Float16 sB[2][128 * 32];
  const int tid = threadIdx.x;
  const int wave = tid >> 6, lane = tid & 63;
  const int quad = lane >> 4, l16 = lane & 15;
  const int wm = wave & 1, wn = wave >> 1;
  const int n0 = blockIdx.x * 128;
  const int m0 = blockIdx.y * 128;
  const int rS = tid >> 2, cS = tid & 3;
  const int csw = (cS ^ ((rS >> 1) & 3)) * 8;  // swizzled source chunk (halfs)

  const _Float16* aR0 = A + (size_t)(m0 + rS) * 1024 + csw;
  const _Float16* aR1 = A + (size_t)(m0 + 64 + rS) * 1024 + csw;
  const _Float16* bR0 = Bw + (size_t)(n0 + rS) * 1024 + csw;
  const _Float16* bR1 = Bw + (size_t)(n0 + 64 + rS) * 1024 + csw;

  f32x4 acc[4][4] = {};

  auto stage = [&](int buf, int k0) {
    cp16(aR0 + k0, &sA[buf][wave * 512]);
    cp16(aR1 + k0, &sA[buf][2048 + wave * 512]);
    cp16(bR0 + k0, &sB[buf][wave * 512]);
    cp16(bR1 + k0, &sB[buf][2048 + wave * 512]);
  };
  auto compute = [&](int cur) {
    half8 a[4], b[4];
#pragma unroll
    for (int m = 0; m < 4; ++m) {
      int row = wm * 64 + m * 16 + l16;
      a[m] = *(const half8*)&sA[cur][row * 32 + ((quad ^ ((row >> 1) & 3)) << 3)];
    }
#pragma unroll
    for (int n = 0; n < 4; ++n) {
      int row = wn * 64 + n * 16 + l16;
      b[n] = *(const half8*)&sB[cur][row * 32 + ((quad ^ ((row >> 1) & 3)) << 3)];
    }
#pragma unroll
    for (int m = 0; m < 4; ++m)
#pragma unroll
      for (int n = 0; n < 4; ++n)
        acc[m][n] = __builtin_amdgcn_mfma_f32_16x16x32_f16(a[m], b[n], acc[m][n], 0, 0, 0);
  };

  stage(0, 0);
  __syncthreads();
  for (int it = 0; it < 31; ++it) {
    const int cur = it & 1;
    stage(cur ^ 1, (it + 1) * 32);
    compute(cur);
    __syncthreads();
  }
  compute(1);  // it=31

#pragma unroll
  for (int m = 0; m < 4; ++m) {
#pragma unroll
    for (int n = 0; n < 4; ++n) {
      const int col = n0 + wn * 64 + n * 16 + l16;
#pragma unroll
      for (int r = 0; r < 4; ++r) {
        const int row = m0 + wm * 64 + m * 16 + quad * 4 + r;
        Xall[(size_t)row * NG + col] =
            (_Float16)(acc[m][n][r] + Xc[(size_t)(row & 511) * NG + col]);
      }
    }
  }
}

// ---------------------------------------------------------------------------
// PERSISTENT recurrent kernel: one launch for all 47 steps.
// 256 blocks (1/CU via 128KiB LDS) x 256 threads (4 waves).
// Block (cb,bb): 16 hidden cols (all 4 gates) x 128 batches.
// Weights: LDS-resident fragments (loaded once, conflict-free reads).
// A (h_prev): global->reg, 4-chunk lookahead, NO barriers in K-loop.
// c: registers across all steps. h: fresh slab per step.
// NEW barrier: block (cb,bb) depends ONLY on the 64 producers sharing bb ->
// 4 independent sub-barriers. Each block STOREs t to its own padded flag
// (no RMW contention), wave 0 polls the 64 peer flags (1 load/lane, read-only
// hot lines), then an acquire threadfence. Replaces the 256-serialized-RMW
// global barrier that cost ~26 us/step (round-3 post-mortem).
// ---------------------------------------------------------------------------
__global__ __launch_bounds__(256, 1) void lstm_all(
    const _Float16* __restrict__ Wf, const _Float16* __restrict__ Xall,
    _Float16* __restrict__ hs, float* __restrict__ out,
    unsigned* __restrict__ bar) {
  __shared__ __align__(16) _Float16 wlds[65536];  // 128 KiB
  const int tid = threadIdx.x;
  const int wave = tid >> 6, lane = tid & 63;
  const int quad = lane >> 4, l16 = lane & 15;
  const int cb = blockIdx.x >> 2, bb = blockIdx.x & 3;
  const int col = cb * 16 + l16;

  // --- weight fragments -> LDS, once (fully coalesced, linear dest)
  {
    const _Float16* src = Wf + (size_t)cb * 65536;
#pragma unroll
    for (int i = 0; i < 32; ++i)
      cp16(src + (size_t)(i * 256 + wave * 64 + lane) * 8,
           wlds + (i * 256 + wave * 64) * 8);
  }
  __syncthreads();

  float cc[2][4] = {{0.f, 0.f, 0.f, 0.f}, {0.f, 0.f, 0.f, 0.f}};

  for (int t = 1; t < T_; ++t) {
    // --- Xall prefetch (T14: issue before K-loop, consume in epilogue)
    _Float16 xh[2][4][4];
    {
      const _Float16* xb =
          Xall + ((size_t)(t - 1) * 512 + bb * 128 + wave * 32) * NG + col;
#pragma unroll
      for (int m = 0; m < 2; ++m)
#pragma unroll
        for (int r = 0; r < 4; ++r) {
          const _Float16* xr = xb + (size_t)(m * 16 + quad * 4 + r) * NG;
#pragma unroll
          for (int n = 0; n < 4; ++n) xh[m][n][r] = xr[n * 1024];
        }
    }

    f32x4 acc[2][4] = {};
    if (t > 1) {
      const _Float16* hp = hs + (size_t)(t - 1) * 524288;
      const _Float16* aB0 = hp + (size_t)(bb * 128 + wave * 32 + l16) * 1024 + quad * 8;
      const _Float16* aB1 = aB0 + 16 * 1024;
      half8 abuf[4][2][2];  // [slot][m][kk] — all indices compile-time (full unroll)
#define LOADA(P, CH)                                      \
  do {                                                    \
    abuf[P][0][0] = *(const half8*)(aB0 + (CH) * 64);      \
    abuf[P][0][1] = *(const half8*)(aB0 + (CH) * 64 + 32); \
    abuf[P][1][0] = *(const half8*)(aB1 + (CH) * 64);      \
    abuf[P][1][1] = *(const half8*)(aB1 + (CH) * 64 + 32); \
  } while (0)
      LOADA(0, 0);
      LOADA(1, 1);
      LOADA(2, 2);
      LOADA(3, 3);
#pragma unroll
      for (int ch = 0; ch < 16; ++ch) {
        half8 bf[2][4];
#pragma unroll
        for (int kk = 0; kk < 2; ++kk)
#pragma unroll
          for (int n = 0; n < 4; ++n)
            bf[kk][n] =
                *(const half8*)&wlds[(size_t)((n * 32 + ch * 2 + kk) * 64 + lane) * 8];
        const int p = ch & 3;
#pragma unroll
        for (int kk = 0; kk < 2; ++kk)
#pragma unroll
          for (int m = 0; m < 2; ++m)
#pragma unroll
            for (int n = 0; n < 4; ++n)
              acc[m][n] = __builtin_amdgcn_mfma_f32_16x16x32_f16(
                  abuf[p][m][kk], bf[kk][n], acc[m][n], 0, 0, 0);
        if (ch < 12) LOADA(p, ch + 4);
      }
#undef LOADA
    }

    // --- epilogue: gates -> c (regs) -> h slab t + out
    _Float16* hw = hs + (size_t)t * 524288;
#pragma unroll
    for (int m = 0; m < 2; ++m)
#pragma unroll
      for (int r = 0; r < 4; ++r) {
        int b = bb * 128 + wave * 32 + m * 16 + quad * 4 + r;
        float iv = acc[m][0][r] + (float)xh[m][0][r];
        float fv = acc[m][1][r] + (float)xh[m][1][r];
        float gv = acc[m][2][r] + (float)xh[m][2][r];
        float ov = acc[m][3][r] + (float)xh[m][3][r];
        float ig = sigmoidf_(iv), fg = sigmoidf_(fv), og = sigmoidf_(ov);
        float gg = tanhf(gv);
        float cn = fg * cc[m][r] + ig * gg;
        cc[m][r] = cn;
        float hv = og * tanhf(cn);
        hw[(size_t)b * 1024 + col] = (_Float16)hv;
        out[(size_t)b * (T_ * H_) + (size_t)t * H_ + col] = hv;
      }

    // --- sub-barrier over the 64 blocks sharing bb (store-only signal)
    __syncthreads();  // vmcnt(0) drain of ALL waves' h stores before the fence
    if (tid == 0) {
      __threadfence();  // agent release: L2 writeback -> h visible cross-XCD
      __hip_atomic_store(&bar[(bb * 64 + cb) * 16], (unsigned)t, __ATOMIC_RELAXED,
                         __HIP_MEMORY_SCOPE_AGENT);
    }
    if (tid < 64) {
      const unsigned* f = bar + (bb * 64 + tid) * 16;
      while (__hip_atomic_load(f, __ATOMIC_RELAXED, __HIP_MEMORY_SCOPE_AGENT) <
             (unsigned)t)
        __builtin_amdgcn_s_sleep(1);
      __threadfence();  // acquire: invalidate stale lines before reading h
    }
    __syncthreads();
  }
}

// ---------------------------------------------------------------------------
extern "C" void kernel_launch(void* const* d_in, const int* in_sizes, int n_in,
                              void* d_out, int out_size, void* d_ws, size_t ws_size,
                              hipStream_t stream) {
  (void)in_sizes; (void)n_in; (void)out_size; (void)ws_size;
  const float* dh   = (const float*)d_in[0];
  // d_in[1] ("outputs") is unused by the reference
  const int*   caps = (const int*)d_in[2];
  const float* W_ih = (const float*)d_in[3];
  const float* W_hh = (const float*)d_in[4];
  const float* b_ih = (const float*)d_in[5];
  const float* b_hh = (const float*)d_in[6];
  float* out = (float*)d_out;

  // Workspace layout (~282.1 MB):
  char* ws = (char*)d_ws;
  _Float16* Wx116 = (_Float16*)(ws);                 //   8,388,608
  _Float16* Wfrag = (_Float16*)(ws + 8388608);       //   8,388,608 (fragment-ordered Whh)
  _Float16* Wp    = (_Float16*)(ws + 16777216);      //   8,388,608
  _Float16* dh16  = (_Float16*)(ws + 25165824);      //  50,331,648 (REUSED as h slabs after gemm_x)
  _Float16* pld16 = (_Float16*)(ws + 75497472);      //   1,048,576
  float*    Xc    = (float*)   (ws + 76546048);      //   8,388,608
  _Float16* Xall  = (_Float16*)(ws + 84934656);      // 197,132,288 (47*512*4096 f16)
  unsigned* bar   = (unsigned*)(ws + 282066944);     //  16,384 B flag region

  prep_w<<<32768, 256, 0, stream>>>(W_ih, Wx116, Wp);
  prep_wfrag<<<2048, 256, 0, stream>>>(W_hh, Wfrag);
  pool_conv<<<2048, 256, 0, stream>>>(dh, caps, dh16, pld16);
  init_zero<<<2048, 256, 0, stream>>>(out, bar);
  gemm_pool<<<dim3(32, 8), 256, 0, stream>>>(pld16, Wp, b_ih, b_hh, Xc);
  // A = dh16 rows from t=1 onward: dh16 + 512*1024 elements, [24064 x 1024] f16
  gemm_x<<<dim3(32, 188), 256, 0, stream>>>(dh16 + 524288, Wx116, Xc, Xall);
  // h slab t (t=1..47) lives at dh16-region byte offset t*1MB (dh16 dead after gemm_x)
  lstm_all<<<256, 256, 0, stream>>>(Wfrag, Xall, dh16, out, bar);
}

// Round 6
// 1403.734 us; speedup vs baseline: 1.4857x; 1.2426x over previous
//
#include <hip/hip_runtime.h>
#include <math.h>
#include <stdint.h>

// Problem constants
#define B_ 512
#define D_ 1024
#define H_ 1024
#define T_ 48
#define NG 4096      // 4*H gate columns

typedef _Float16 half8 __attribute__((ext_vector_type(8)));
typedef float f32x4 __attribute__((ext_vector_type(4)));

// Agent-scope (device-coherent, IF$-level) helpers — compiler-generated ops only.
#define AG_LOAD(p)      __hip_atomic_load((p), __ATOMIC_RELAXED, __HIP_MEMORY_SCOPE_AGENT)
#define AG_STORE(p, v)  __hip_atomic_store((p), (v), __ATOMIC_RELAXED, __HIP_MEMORY_SCOPE_AGENT)

// Async global->LDS, 16B per lane. LDS dest must be wave-uniform base; HW adds lane*16.
__device__ __forceinline__ void cp16(const void* g, void* l) {
  __builtin_amdgcn_global_load_lds(
      (__attribute__((address_space(1))) const unsigned int*)(uintptr_t)g,
      (__attribute__((address_space(3))) unsigned int*)(uintptr_t)l, 16, 0, 0);
}

__device__ __forceinline__ float sigmoidf_(float x) { return 1.0f / (1.0f + expf(-x)); }

// ---------------------------------------------------------------------------
// Prep: Wx1[j][k]=W_ih[j][k] (k<1024) f16; Wp[j][k]=W_ih[j][1024+k] f16
// ---------------------------------------------------------------------------
__global__ void prep_w(const float* __restrict__ W_ih,
                       _Float16* __restrict__ Wx1, _Float16* __restrict__ Wp) {
  int idx = blockIdx.x * 256 + threadIdx.x;  // < 8388608
  const int n1 = NG * H_;  // 4,194,304
  if (idx < n1) {
    int j = idx >> 10, k = idx & 1023;
    Wx1[idx] = (_Float16)W_ih[j * 2048 + k];
  } else {
    int i3 = idx - n1;
    int j = i3 >> 10, k = i3 & 1023;
    Wp[i3] = (_Float16)W_ih[j * 2048 + 1024 + k];
  }
}

// ---------------------------------------------------------------------------
// Whh -> MFMA B-fragment order, per column-block cb (16 hidden cols).
// Fragment f = ((cb*4 + n)*32 + kc)*64 + lane holds half8:
//   B[row = n*1024 + cb*16 + (lane&15)][k = kc*32 + (lane>>4)*8 .. +8]
// ---------------------------------------------------------------------------
__global__ void prep_wfrag(const float* __restrict__ W_hh, _Float16* __restrict__ Wf) {
  int f = blockIdx.x * 256 + threadIdx.x;  // < 524288
  int cb = f >> 13;
  int rem = f & 8191;
  int n = rem >> 11;
  int kc = (rem >> 6) & 31;
  int lane = rem & 63;
  int l16 = lane & 15, quad = lane >> 4;
  const float* s = W_hh + (size_t)(n * 1024 + cb * 16 + l16) * 1024 + kc * 32 + quad * 8;
  half8 v;
#pragma unroll
  for (int i = 0; i < 8; ++i) v[i] = (_Float16)s[i];
  *(half8*)(Wf + (size_t)f * 8) = v;
}

// ---------------------------------------------------------------------------
// Pool: pooled[b][d] = sum_t mask(t,b)*dh[t][b][d] / sum_t mask(t,b); also dh->f16 (t>=1)
// ---------------------------------------------------------------------------
__global__ void pool_conv(const float* __restrict__ dh, const int* __restrict__ caps,
                          _Float16* __restrict__ dh16, _Float16* __restrict__ pooled16) {
  int tid = blockIdx.x * 256 + threadIdx.x;  // b*1024 + d, < 524288
  int b = tid >> 10;
  float sum = 0.0f, cnt = 0.0f;
  for (int t = 0; t < T_; ++t) {
    int cap = caps[t * B_ + b];
    float v = dh[(size_t)t * (B_ * D_) + tid];
    if (cap != 0 && cap != 2) { sum += v; cnt += 1.0f; }
    if (t >= 1) dh16[(size_t)t * (B_ * D_) + tid] = (_Float16)v;
  }
  pooled16[tid] = (_Float16)(sum / cnt);
}

// ---------------------------------------------------------------------------
// Init: feats[:,0,:]=0, barrier flags = 0 (AGENT-scope so the zeros are at the
// IF$ coherence point before lstm_all's agent-scope polls read them).
// ---------------------------------------------------------------------------
__global__ void init_zero(float* __restrict__ out, unsigned* __restrict__ bar) {
  int tid = blockIdx.x * 256 + threadIdx.x;  // < 524288
  int b = tid >> 10, d = tid & 1023;
  out[(size_t)b * (T_ * H_) + d] = 0.0f;
  if (tid < 4096) AG_STORE(&bar[tid], 0u);
}

// ---------------------------------------------------------------------------
// Xc[b][n] = sum_k pooled[b][k]*Wp[n][k] + b_ih[n] + b_hh[n]   (f32, B x 4096)
// ---------------------------------------------------------------------------
__global__ __launch_bounds__(256) void gemm_pool(
    const _Float16* __restrict__ A, const _Float16* __restrict__ Wp,
    const float* __restrict__ b_ih, const float* __restrict__ b_hh,
    float* __restrict__ Xc) {
  __shared__ __align__(16) _Float16 sA[64 * 32];
  __shared__ __align__(16) _Float16 sB[128 * 32];
  const int tid = threadIdx.x;
  const int wave = tid >> 6, lane = tid & 63;
  const int quad = lane >> 4, l16 = lane & 15;
  const int wm = wave & 1, wn = wave >> 1;
  const int n0 = blockIdx.x * 128;
  const int b0 = blockIdx.y * 64;
  const int rS = tid >> 2, cS = tid & 3;

  f32x4 acc[2][4] = {};
  for (int k0 = 0; k0 < 1024; k0 += 32) {
    cp16(A + (size_t)(b0 + rS) * 1024 + k0 + cS * 8, sA + wave * 512);
    cp16(Wp + (size_t)(n0 + rS) * 1024 + k0 + cS * 8, sB + wave * 512);
    cp16(Wp + (size_t)(n0 + 64 + rS) * 1024 + k0 + cS * 8, sB + 2048 + wave * 512);
    __syncthreads();
    half8 a[2], bfr[4];
#pragma unroll
    for (int m = 0; m < 2; ++m)
      a[m] = *(const half8*)(sA + (wm * 32 + m * 16 + l16) * 32 + quad * 8);
#pragma unroll
    for (int n = 0; n < 4; ++n)
      bfr[n] = *(const half8*)(sB + (wn * 64 + n * 16 + l16) * 32 + quad * 8);
#pragma unroll
    for (int m = 0; m < 2; ++m)
#pragma unroll
      for (int n = 0; n < 4; ++n)
        acc[m][n] = __builtin_amdgcn_mfma_f32_16x16x32_f16(a[m], bfr[n], acc[m][n], 0, 0, 0);
    __syncthreads();
  }
#pragma unroll
  for (int m = 0; m < 2; ++m) {
#pragma unroll
    for (int n = 0; n < 4; ++n) {
      int nn = n0 + wn * 64 + n * 16 + l16;
      float bias = b_ih[nn] + b_hh[nn];
#pragma unroll
      for (int r = 0; r < 4; ++r) {
        int bb = b0 + wm * 32 + m * 16 + quad * 4 + r;
        Xc[(size_t)bb * NG + nn] = acc[m][n][r] + bias;
      }
    }
  }
}

// ---------------------------------------------------------------------------
// Big input-projection GEMM: Xall[r][n] (f16) = sum_k A[r][k]*Wx1[n][k] + Xc[r&511][n]
// M=24064, N=4096, K=1024. 128x128 tile, 2-phase double-buffered LDS.
// REVERTED to the round-2 verified version (no swizzle) — one variable/round.
// ---------------------------------------------------------------------------
__global__ __launch_bounds__(256) void gemm_x(
    const _Float16* __restrict__ A, const _Float16* __restrict__ Bw,
    const float* __restrict__ Xc, _Float16* __restrict__ Xall) {
  __shared__ __align__(16) _Float16 sA[2][128 * 32];
  __shared__ __align__(16) _Float16 sB[2][128 * 32];
  const int tid = threadIdx.x;
  const int wave = tid >> 6, lane = tid & 63;
  const int quad = lane >> 4, l16 = lane & 15;
  const int wm = wave & 1, wn = wave >> 1;
  const int n0 = blockIdx.x * 128;
  const int m0 = blockIdx.y * 128;
  const int rS = tid >> 2, cS = tid & 3;

  const _Float16* aR0 = A + (size_t)(m0 + rS) * 1024 + cS * 8;
  const _Float16* aR1 = A + (size_t)(m0 + 64 + rS) * 1024 + cS * 8;
  const _Float16* bR0 = Bw + (size_t)(n0 + rS) * 1024 + cS * 8;
  const _Float16* bR1 = Bw + (size_t)(n0 + 64 + rS) * 1024 + cS * 8;

  f32x4 acc[4][4] = {};

  auto stage = [&](int buf, int k0) {
    cp16(aR0 + k0, &sA[buf][wave * 512]);
    cp16(aR1 + k0, &sA[buf][2048 + wave * 512]);
    cp16(bR0 + k0, &sB[buf][wave * 512]);
    cp16(bR1 + k0, &sB[buf][2048 + wave * 512]);
  };
  auto compute = [&](int cur) {
    half8 a[4], b[4];
#pragma unroll
    for (int m = 0; m < 4; ++m)
      a[m] = *(const half8*)&sA[cur][(wm * 64 + m * 16 + l16) * 32 + quad * 8];
#pragma unroll
    for (int n = 0; n < 4; ++n)
      b[n] = *(const half8*)&sB[cur][(wn * 64 + n * 16 + l16) * 32 + quad * 8];
#pragma unroll
    for (int m = 0; m < 4; ++m)
#pragma unroll
      for (int n = 0; n < 4; ++n)
        acc[m][n] = __builtin_amdgcn_mfma_f32_16x16x32_f16(a[m], b[n], acc[m][n], 0, 0, 0);
  };

  stage(0, 0);
  __syncthreads();
  for (int it = 0; it < 31; ++it) {
    const int cur = it & 1;
    stage(cur ^ 1, (it + 1) * 32);
    compute(cur);
    __syncthreads();
  }
  compute(1);  // it=31

#pragma unroll
  for (int m = 0; m < 4; ++m) {
#pragma unroll
    for (int n = 0; n < 4; ++n) {
      const int col = n0 + wn * 64 + n * 16 + l16;
#pragma unroll
      for (int r = 0; r < 4; ++r) {
        const int row = m0 + wm * 64 + m * 16 + quad * 4 + r;
        Xall[(size_t)row * NG + col] =
            (_Float16)(acc[m][n][r] + Xc[(size_t)(row & 511) * NG + col]);
      }
    }
  }
}

// ---------------------------------------------------------------------------
// PERSISTENT recurrent kernel, coherence-by-construction (no fences, no asm):
//  - h stores: relaxed AGENT atomics (2B) -> land at IF$ coherence point.
//  - h loads:  relaxed AGENT atomics (8B) -> read IF$ directly. Never touch
//    the non-coherent L2s, so no wbl2/inv fences and no stale lines from
//    previous graph replays (round-5's latent bug).
//  - Ordering: stores -> __syncthreads (compiler emits full vmcnt(0) drain
//    before s_barrier) -> flag store -> poll peers -> __syncthreads.
//  - Flag machinery identical to the PASSING round-4 kernel (store-only
//    signal, 64-peer poll per bb-group), plus a bounded spin so a protocol
//    bug can only fail verification, never hang the container.
// ---------------------------------------------------------------------------
__global__ __launch_bounds__(256, 1) void lstm_all(
    const _Float16* __restrict__ Wf, const _Float16* __restrict__ Xall,
    _Float16* __restrict__ hs, float* __restrict__ out,
    unsigned* __restrict__ bar) {
  __shared__ __align__(16) _Float16 wlds[65536];  // 128 KiB
  const int tid = threadIdx.x;
  const int wave = tid >> 6, lane = tid & 63;
  const int quad = lane >> 4, l16 = lane & 15;
  const int cb = blockIdx.x >> 2, bb = blockIdx.x & 3;
  const int col = cb * 16 + l16;

  // --- weight fragments -> LDS, once (fully coalesced, linear dest)
  {
    const _Float16* src = Wf + (size_t)cb * 65536;
#pragma unroll
    for (int i = 0; i < 32; ++i)
      cp16(src + (size_t)(i * 256 + wave * 64 + lane) * 8,
           wlds + (i * 256 + wave * 64) * 8);
  }
  __syncthreads();

  float cc[2][4] = {{0.f, 0.f, 0.f, 0.f}, {0.f, 0.f, 0.f, 0.f}};

  // Xall prefetch registers (filled for step t before its iteration begins)
  _Float16 xh[2][4][4];
  auto prefetchX = [&](int t) {
    const _Float16* xb =
        Xall + ((size_t)(t - 1) * 512 + bb * 128 + wave * 32) * NG + col;
#pragma unroll
    for (int m = 0; m < 2; ++m)
#pragma unroll
      for (int r = 0; r < 4; ++r) {
        const _Float16* xr = xb + (size_t)(m * 16 + quad * 4 + r) * NG;
#pragma unroll
        for (int n = 0; n < 4; ++n) xh[m][n][r] = xr[n * 1024];
      }
  };
  prefetchX(1);

  union U16 { unsigned long long u[2]; half8 h; };

  for (int t = 1; t < T_; ++t) {
    f32x4 acc[2][4] = {};
    if (t > 1) {
      const _Float16* hp = hs + (size_t)(t - 1) * 524288;
      const _Float16* aB0 = hp + (size_t)(bb * 128 + wave * 32 + l16) * 1024 + quad * 8;
      const _Float16* aB1 = aB0 + 16 * 1024;
      half8 abuf[4][2][2];  // [slot][m][kk] — all indices compile-time (full unroll)
#define LOADA(P, CH)                                                        \
  do {                                                                      \
    const unsigned long long* q00 =                                         \
        (const unsigned long long*)(aB0 + (CH) * 64);                       \
    const unsigned long long* q01 =                                         \
        (const unsigned long long*)(aB0 + (CH) * 64 + 32);                  \
    const unsigned long long* q10 =                                         \
        (const unsigned long long*)(aB1 + (CH) * 64);                       \
    const unsigned long long* q11 =                                         \
        (const unsigned long long*)(aB1 + (CH) * 64 + 32);                  \
    U16 t00, t01, t10, t11;                                                 \
    t00.u[0] = AG_LOAD(q00); t00.u[1] = AG_LOAD(q00 + 1);                   \
    t01.u[0] = AG_LOAD(q01); t01.u[1] = AG_LOAD(q01 + 1);                   \
    t10.u[0] = AG_LOAD(q10); t10.u[1] = AG_LOAD(q10 + 1);                   \
    t11.u[0] = AG_LOAD(q11); t11.u[1] = AG_LOAD(q11 + 1);                   \
    abuf[P][0][0] = t00.h; abuf[P][0][1] = t01.h;                           \
    abuf[P][1][0] = t10.h; abuf[P][1][1] = t11.h;                           \
  } while (0)
      LOADA(0, 0);
      LOADA(1, 1);
      LOADA(2, 2);
      LOADA(3, 3);
#pragma unroll
      for (int ch = 0; ch < 16; ++ch) {
        half8 bf[2][4];
#pragma unroll
        for (int kk = 0; kk < 2; ++kk)
#pragma unroll
          for (int n = 0; n < 4; ++n)
            bf[kk][n] =
                *(const half8*)&wlds[(size_t)((n * 32 + ch * 2 + kk) * 64 + lane) * 8];
        const int p = ch & 3;
#pragma unroll
        for (int kk = 0; kk < 2; ++kk)
#pragma unroll
          for (int m = 0; m < 2; ++m)
#pragma unroll
            for (int n = 0; n < 4; ++n)
              acc[m][n] = __builtin_amdgcn_mfma_f32_16x16x32_f16(
                  abuf[p][m][kk], bf[kk][n], acc[m][n], 0, 0, 0);
        if (ch < 12) LOADA(p, ch + 4);
      }
#undef LOADA
    }

    // --- epilogue: gates -> c (regs) -> h slab t (agent-coherent) + out
    _Float16* hw = hs + (size_t)t * 524288;
#pragma unroll
    for (int m = 0; m < 2; ++m)
#pragma unroll
      for (int r = 0; r < 4; ++r) {
        int b = bb * 128 + wave * 32 + m * 16 + quad * 4 + r;
        float iv = acc[m][0][r] + (float)xh[m][0][r];
        float fv = acc[m][1][r] + (float)xh[m][1][r];
        float gv = acc[m][2][r] + (float)xh[m][2][r];
        float ov = acc[m][3][r] + (float)xh[m][3][r];
        float ig = sigmoidf_(iv), fg = sigmoidf_(fv), og = sigmoidf_(ov);
        float gg = tanhf(gv);
        float cn = fg * cc[m][r] + ig * gg;
        cc[m][r] = cn;
        float hv = og * tanhf(cn);
        _Float16 hv16 = (_Float16)hv;
        AG_STORE((unsigned short*)(hw + (size_t)b * 1024 + col),
                 __builtin_bit_cast(unsigned short, hv16));
        out[(size_t)b * (T_ * H_) + (size_t)t * H_ + col] = hv;
      }

    if (t + 1 < T_) {
      __syncthreads();  // compiler-emitted vmcnt(0) drain: h stores at IF$
      if (tid == 0)
        AG_STORE(&bar[(bb * 64 + cb) * 16], (unsigned)t);
      prefetchX(t + 1);  // drains while wave 0 polls
      if (tid < 64) {
        const unsigned* f = bar + (bb * 64 + tid) * 16;
        // bounded spin: a protocol bug fails verification instead of hanging
        for (int spin = 0; spin < (1 << 20); ++spin) {
          if (AG_LOAD(f) >= (unsigned)t) break;
          __builtin_amdgcn_s_sleep(1);
        }
      }
      __syncthreads();
    }
  }
}

// ---------------------------------------------------------------------------
extern "C" void kernel_launch(void* const* d_in, const int* in_sizes, int n_in,
                              void* d_out, int out_size, void* d_ws, size_t ws_size,
                              hipStream_t stream) {
  (void)in_sizes; (void)n_in; (void)out_size; (void)ws_size;
  const float* dh   = (const float*)d_in[0];
  // d_in[1] ("outputs") is unused by the reference
  const int*   caps = (const int*)d_in[2];
  const float* W_ih = (const float*)d_in[3];
  const float* W_hh = (const float*)d_in[4];
  const float* b_ih = (const float*)d_in[5];
  const float* b_hh = (const float*)d_in[6];
  float* out = (float*)d_out;

  // Workspace layout (~282.1 MB):
  char* ws = (char*)d_ws;
  _Float16* Wx116 = (_Float16*)(ws);                 //   8,388,608
  _Float16* Wfrag = (_Float16*)(ws + 8388608);       //   8,388,608 (fragment-ordered Whh)
  _Float16* Wp    = (_Float16*)(ws + 16777216);      //   8,388,608
  _Float16* dh16  = (_Float16*)(ws + 25165824);      //  50,331,648 (REUSED as h slabs after gemm_x)
  _Float16* pld16 = (_Float16*)(ws + 75497472);      //   1,048,576
  float*    Xc    = (float*)   (ws + 76546048);      //   8,388,608
  _Float16* Xall  = (_Float16*)(ws + 84934656);      // 197,132,288 (47*512*4096 f16)
  unsigned* bar   = (unsigned*)(ws + 282066944);     //  16,384 B flag region

  prep_w<<<32768, 256, 0, stream>>>(W_ih, Wx116, Wp);
  prep_wfrag<<<2048, 256, 0, stream>>>(W_hh, Wfrag);
  pool_conv<<<2048, 256, 0, stream>>>(dh, caps, dh16, pld16);
  init_zero<<<2048, 256, 0, stream>>>(out, bar);
  gemm_pool<<<dim3(32, 8), 256, 0, stream>>>(pld16, Wp, b_ih, b_hh, Xc);
  // A = dh16 rows from t=1 onward: dh16 + 512*1024 elements, [24064 x 1024] f16
  gemm_x<<<dim3(32, 188), 256, 0, stream>>>(dh16 + 524288, Wx116, Xc, Xall);
  // h slab t (t=1..47) lives at dh16-region byte offset t*1MB (dh16 dead after gemm_x)
  lstm_all<<<256, 256, 0, stream>>>(Wfrag, Xall, dh16, out, bar);
}

// Round 7
// 1189.856 us; speedup vs baseline: 1.7527x; 1.1798x over previous
//
#include <hip/hip_runtime.h>
#include <math.h>
#include <stdint.h>

// Problem constants
#define B_ 512
#define D_ 1024
#define H_ 1024
#define T_ 48
#define NG 4096      // 4*H gate columns

typedef _Float16 half8 __attribute__((ext_vector_type(8)));
typedef float f32x4 __attribute__((ext_vector_type(4)));

// Agent-scope (device-coherent) helpers — compiler-generated ops only.
#define AG_LOAD(p)      __hip_atomic_load((p), __ATOMIC_RELAXED, __HIP_MEMORY_SCOPE_AGENT)
#define AG_STORE(p, v)  __hip_atomic_store((p), (v), __ATOMIC_RELAXED, __HIP_MEMORY_SCOPE_AGENT)

// Async global->LDS, 16B per lane. LDS dest must be wave-uniform base; HW adds lane*16.
__device__ __forceinline__ void cp16(const void* g, void* l) {
  __builtin_amdgcn_global_load_lds(
      (__attribute__((address_space(1))) const unsigned int*)(uintptr_t)g,
      (__attribute__((address_space(3))) unsigned int*)(uintptr_t)l, 16, 0, 0);
}

__device__ __forceinline__ float sigmoidf_(float x) { return 1.0f / (1.0f + expf(-x)); }

// ---------------------------------------------------------------------------
// Prep: Wx1[j][k]=W_ih[j][k] (k<1024) f16; Wp[j][k]=W_ih[j][1024+k] f16
// ---------------------------------------------------------------------------
__global__ void prep_w(const float* __restrict__ W_ih,
                       _Float16* __restrict__ Wx1, _Float16* __restrict__ Wp) {
  int idx = blockIdx.x * 256 + threadIdx.x;  // < 8388608
  const int n1 = NG * H_;  // 4,194,304
  if (idx < n1) {
    int j = idx >> 10, k = idx & 1023;
    Wx1[idx] = (_Float16)W_ih[j * 2048 + k];
  } else {
    int i3 = idx - n1;
    int j = i3 >> 10, k = i3 & 1023;
    Wp[i3] = (_Float16)W_ih[j * 2048 + 1024 + k];
  }
}

// ---------------------------------------------------------------------------
// Whh -> MFMA B-fragment order, per column-block cb (16 hidden cols).
// Fragment f = ((cb*4 + n)*32 + kc)*64 + lane holds half8:
//   B[row = n*1024 + cb*16 + (lane&15)][k = kc*32 + (lane>>4)*8 .. +8]
// ---------------------------------------------------------------------------
__global__ void prep_wfrag(const float* __restrict__ W_hh, _Float16* __restrict__ Wf) {
  int f = blockIdx.x * 256 + threadIdx.x;  // < 524288
  int cb = f >> 13;
  int rem = f & 8191;
  int n = rem >> 11;
  int kc = (rem >> 6) & 31;
  int lane = rem & 63;
  int l16 = lane & 15, quad = lane >> 4;
  const float* s = W_hh + (size_t)(n * 1024 + cb * 16 + l16) * 1024 + kc * 32 + quad * 8;
  half8 v;
#pragma unroll
  for (int i = 0; i < 8; ++i) v[i] = (_Float16)s[i];
  *(half8*)(Wf + (size_t)f * 8) = v;
}

// ---------------------------------------------------------------------------
// Pool: pooled[b][d] = sum_t mask(t,b)*dh[t][b][d] / sum_t mask(t,b); also dh->f16 (t>=1)
// ---------------------------------------------------------------------------
__global__ void pool_conv(const float* __restrict__ dh, const int* __restrict__ caps,
                          _Float16* __restrict__ dh16, _Float16* __restrict__ pooled16) {
  int tid = blockIdx.x * 256 + threadIdx.x;  // b*1024 + d, < 524288
  int b = tid >> 10;
  float sum = 0.0f, cnt = 0.0f;
  for (int t = 0; t < T_; ++t) {
    int cap = caps[t * B_ + b];
    float v = dh[(size_t)t * (B_ * D_) + tid];
    if (cap != 0 && cap != 2) { sum += v; cnt += 1.0f; }
    if (t >= 1) dh16[(size_t)t * (B_ * D_) + tid] = (_Float16)v;
  }
  pooled16[tid] = (_Float16)(sum / cnt);
}

// ---------------------------------------------------------------------------
// Init: feats[:,0,:]=0, barrier flags = 0 (AGENT-scope; at the coherence point
// before lstm_all's agent-scope polls read them).
// ---------------------------------------------------------------------------
__global__ void init_zero(float* __restrict__ out, unsigned* __restrict__ bar) {
  int tid = blockIdx.x * 256 + threadIdx.x;  // < 524288
  int b = tid >> 10, d = tid & 1023;
  out[(size_t)b * (T_ * H_) + d] = 0.0f;
  if (tid < 4096) AG_STORE(&bar[tid], 0u);
}

// ---------------------------------------------------------------------------
// Xc[b][n] = sum_k pooled[b][k]*Wp[n][k] + b_ih[n] + b_hh[n]   (f32, B x 4096)
// ---------------------------------------------------------------------------
__global__ __launch_bounds__(256) void gemm_pool(
    const _Float16* __restrict__ A, const _Float16* __restrict__ Wp,
    const float* __restrict__ b_ih, const float* __restrict__ b_hh,
    float* __restrict__ Xc) {
  __shared__ __align__(16) _Float16 sA[64 * 32];
  __shared__ __align__(16) _Float16 sB[128 * 32];
  const int tid = threadIdx.x;
  const int wave = tid >> 6, lane = tid & 63;
  const int quad = lane >> 4, l16 = lane & 15;
  const int wm = wave & 1, wn = wave >> 1;
  const int n0 = blockIdx.x * 128;
  const int b0 = blockIdx.y * 64;
  const int rS = tid >> 2, cS = tid & 3;

  f32x4 acc[2][4] = {};
  for (int k0 = 0; k0 < 1024; k0 += 32) {
    cp16(A + (size_t)(b0 + rS) * 1024 + k0 + cS * 8, sA + wave * 512);
    cp16(Wp + (size_t)(n0 + rS) * 1024 + k0 + cS * 8, sB + wave * 512);
    cp16(Wp + (size_t)(n0 + 64 + rS) * 1024 + k0 + cS * 8, sB + 2048 + wave * 512);
    __syncthreads();
    half8 a[2], bfr[4];
#pragma unroll
    for (int m = 0; m < 2; ++m)
      a[m] = *(const half8*)(sA + (wm * 32 + m * 16 + l16) * 32 + quad * 8);
#pragma unroll
    for (int n = 0; n < 4; ++n)
      bfr[n] = *(const half8*)(sB + (wn * 64 + n * 16 + l16) * 32 + quad * 8);
#pragma unroll
    for (int m = 0; m < 2; ++m)
#pragma unroll
      for (int n = 0; n < 4; ++n)
        acc[m][n] = __builtin_amdgcn_mfma_f32_16x16x32_f16(a[m], bfr[n], acc[m][n], 0, 0, 0);
    __syncthreads();
  }
#pragma unroll
  for (int m = 0; m < 2; ++m) {
#pragma unroll
    for (int n = 0; n < 4; ++n) {
      int nn = n0 + wn * 64 + n * 16 + l16;
      float bias = b_ih[nn] + b_hh[nn];
#pragma unroll
      for (int r = 0; r < 4; ++r) {
        int bb = b0 + wm * 32 + m * 16 + quad * 4 + r;
        Xc[(size_t)bb * NG + nn] = acc[m][n][r] + bias;
      }
    }
  }
}

// ---------------------------------------------------------------------------
// Big input-projection GEMM: Xall[r][n] (f16) = sum_k A[r][k]*Wx1[n][k] + Xc[r&511][n]
// M=24064, N=4096, K=1024. 128x128 tile, 2-phase double-buffered LDS.
// Verified round-2 version, unchanged. (Default blockIdx->XCD round-robin
// already gives each XCD a resident 1MB B-slice reused across all 188 row
// tiles — analyzed and kept.)
// ---------------------------------------------------------------------------
__global__ __launch_bounds__(256) void gemm_x(
    const _Float16* __restrict__ A, const _Float16* __restrict__ Bw,
    const float* __restrict__ Xc, _Float16* __restrict__ Xall) {
  __shared__ __align__(16) _Float16 sA[2][128 * 32];
  __shared__ __align__(16) _Float16 sB[2][128 * 32];
  const int tid = threadIdx.x;
  const int wave = tid >> 6, lane = tid & 63;
  const int quad = lane >> 4, l16 = lane & 15;
  const int wm = wave & 1, wn = wave >> 1;
  const int n0 = blockIdx.x * 128;
  const int m0 = blockIdx.y * 128;
  const int rS = tid >> 2, cS = tid & 3;

  const _Float16* aR0 = A + (size_t)(m0 + rS) * 1024 + cS * 8;
  const _Float16* aR1 = A + (size_t)(m0 + 64 + rS) * 1024 + cS * 8;
  const _Float16* bR0 = Bw + (size_t)(n0 + rS) * 1024 + cS * 8;
  const _Float16* bR1 = Bw + (size_t)(n0 + 64 + rS) * 1024 + cS * 8;

  f32x4 acc[4][4] = {};

  auto stage = [&](int buf, int k0) {
    cp16(aR0 + k0, &sA[buf][wave * 512]);
    cp16(aR1 + k0, &sA[buf][2048 + wave * 512]);
    cp16(bR0 + k0, &sB[buf][wave * 512]);
    cp16(bR1 + k0, &sB[buf][2048 + wave * 512]);
  };
  auto compute = [&](int cur) {
    half8 a[4], b[4];
#pragma unroll
    for (int m = 0; m < 4; ++m)
      a[m] = *(const half8*)&sA[cur][(wm * 64 + m * 16 + l16) * 32 + quad * 8];
#pragma unroll
    for (int n = 0; n < 4; ++n)
      b[n] = *(const half8*)&sB[cur][(wn * 64 + n * 16 + l16) * 32 + quad * 8];
#pragma unroll
    for (int m = 0; m < 4; ++m)
#pragma unroll
      for (int n = 0; n < 4; ++n)
        acc[m][n] = __builtin_amdgcn_mfma_f32_16x16x32_f16(a[m], b[n], acc[m][n], 0, 0, 0);
  };

  stage(0, 0);
  __syncthreads();
  for (int it = 0; it < 31; ++it) {
    const int cur = it & 1;
    stage(cur ^ 1, (it + 1) * 32);
    compute(cur);
    __syncthreads();
  }
  compute(1);  // it=31

#pragma unroll
  for (int m = 0; m < 4; ++m) {
#pragma unroll
    for (int n = 0; n < 4; ++n) {
      const int col = n0 + wn * 64 + n * 16 + l16;
#pragma unroll
      for (int r = 0; r < 4; ++r) {
        const int row = m0 + wm * 64 + m * 16 + quad * 4 + r;
        Xall[(size_t)row * NG + col] =
            (_Float16)(acc[m][n][r] + Xc[(size_t)(row & 511) * NG + col]);
      }
    }
  }
}

// ---------------------------------------------------------------------------
// PERSISTENT recurrent kernel.
// Round-7 change (single variable): h loads are PLAIN global loads
// (global_load_dwordx4, vmcnt-only). Round-6's generic-pointer atomic loads
// lowered to flat_load, which increments BOTH vmcnt and lgkmcnt — so every
// LDS-fragment s_waitcnt lgkmcnt(N) before the MFMA cluster also drained the
// in-flight h loads, destroying the 4-slot lookahead (19.7 us/step, MfmaUtil
// 8.7%). Plain loads restore independent counters + L2 reuse.
// Correctness of cached consumer loads without fences:
//  (a) dispatch-start acquire invalidates L2s (this already makes the
//      gemm_x->lstm_all Xall handoff correct, proven rounds 2-6);
//  (b) slab-t lines enter a consumer L2 only via demand misses AFTER the
//      flag poll (control dep + __syncthreads + sched_barrier(0));
//  (c) producer h stores are agent-scope (coherence point) and drained by
//      the __syncthreads vmcnt(0) before the flag store; no stale L2 lines;
//  (d) replays re-invalidate at each dispatch start.
// Store + flag machinery byte-identical to the twice-passing round-6 kernel.
// ---------------------------------------------------------------------------
__global__ __launch_bounds__(256, 1) void lstm_all(
    const _Float16* __restrict__ Wf, const _Float16* __restrict__ Xall,
    _Float16* __restrict__ hs, float* __restrict__ out,
    unsigned* __restrict__ bar) {
  __shared__ __align__(16) _Float16 wlds[65536];  // 128 KiB
  const int tid = threadIdx.x;
  const int wave = tid >> 6, lane = tid & 63;
  const int quad = lane >> 4, l16 = lane & 15;
  const int cb = blockIdx.x >> 2, bb = blockIdx.x & 3;
  const int col = cb * 16 + l16;

  // --- weight fragments -> LDS, once (fully coalesced, linear dest)
  {
    const _Float16* src = Wf + (size_t)cb * 65536;
#pragma unroll
    for (int i = 0; i < 32; ++i)
      cp16(src + (size_t)(i * 256 + wave * 64 + lane) * 8,
           wlds + (i * 256 + wave * 64) * 8);
  }
  __syncthreads();

  float cc[2][4] = {{0.f, 0.f, 0.f, 0.f}, {0.f, 0.f, 0.f, 0.f}};

  // Xall prefetch registers (filled for step t before its iteration begins)
  _Float16 xh[2][4][4];
  auto prefetchX = [&](int t) {
    const _Float16* xb =
        Xall + ((size_t)(t - 1) * 512 + bb * 128 + wave * 32) * NG + col;
#pragma unroll
    for (int m = 0; m < 2; ++m)
#pragma unroll
      for (int r = 0; r < 4; ++r) {
        const _Float16* xr = xb + (size_t)(m * 16 + quad * 4 + r) * NG;
#pragma unroll
        for (int n = 0; n < 4; ++n) xh[m][n][r] = xr[n * 1024];
      }
  };
  prefetchX(1);

  for (int t = 1; t < T_; ++t) {
    f32x4 acc[2][4] = {};
    if (t > 1) {
      const _Float16* hp = hs + (size_t)(t - 1) * 524288;
      const _Float16* aB0 = hp + (size_t)(bb * 128 + wave * 32 + l16) * 1024 + quad * 8;
      const _Float16* aB1 = aB0 + 16 * 1024;
      half8 abuf[4][2][2];  // [slot][m][kk] — all indices compile-time (full unroll)
#define LOADA(P, CH)                                      \
  do {                                                    \
    abuf[P][0][0] = *(const half8*)(aB0 + (CH) * 64);      \
    abuf[P][0][1] = *(const half8*)(aB0 + (CH) * 64 + 32); \
    abuf[P][1][0] = *(const half8*)(aB1 + (CH) * 64);      \
    abuf[P][1][1] = *(const half8*)(aB1 + (CH) * 64 + 32); \
  } while (0)
      LOADA(0, 0);
      LOADA(1, 1);
      LOADA(2, 2);
      LOADA(3, 3);
#pragma unroll
      for (int ch = 0; ch < 16; ++ch) {
        half8 bf[2][4];
#pragma unroll
        for (int kk = 0; kk < 2; ++kk)
#pragma unroll
          for (int n = 0; n < 4; ++n)
            bf[kk][n] =
                *(const half8*)&wlds[(size_t)((n * 32 + ch * 2 + kk) * 64 + lane) * 8];
        const int p = ch & 3;
#pragma unroll
        for (int kk = 0; kk < 2; ++kk)
#pragma unroll
          for (int m = 0; m < 2; ++m)
#pragma unroll
            for (int n = 0; n < 4; ++n)
              acc[m][n] = __builtin_amdgcn_mfma_f32_16x16x32_f16(
                  abuf[p][m][kk], bf[kk][n], acc[m][n], 0, 0, 0);
        if (ch < 12) LOADA(p, ch + 4);
      }
#undef LOADA
    }

    // --- epilogue: gates -> c (regs) -> h slab t (agent-coherent) + out
    _Float16* hw = hs + (size_t)t * 524288;
#pragma unroll
    for (int m = 0; m < 2; ++m)
#pragma unroll
      for (int r = 0; r < 4; ++r) {
        int b = bb * 128 + wave * 32 + m * 16 + quad * 4 + r;
        float iv = acc[m][0][r] + (float)xh[m][0][r];
        float fv = acc[m][1][r] + (float)xh[m][1][r];
        float gv = acc[m][2][r] + (float)xh[m][2][r];
        float ov = acc[m][3][r] + (float)xh[m][3][r];
        float ig = sigmoidf_(iv), fg = sigmoidf_(fv), og = sigmoidf_(ov);
        float gg = tanhf(gv);
        float cn = fg * cc[m][r] + ig * gg;
        cc[m][r] = cn;
        float hv = og * tanhf(cn);
        _Float16 hv16 = (_Float16)hv;
        AG_STORE((unsigned short*)(hw + (size_t)b * 1024 + col),
                 __builtin_bit_cast(unsigned short, hv16));
        out[(size_t)b * (T_ * H_) + (size_t)t * H_ + col] = hv;
      }

    if (t + 1 < T_) {
      __syncthreads();  // compiler-emitted vmcnt(0) drain: h stores at coherence pt
      if (tid == 0)
        AG_STORE(&bar[(bb * 64 + cb) * 16], (unsigned)t);
      prefetchX(t + 1);  // drains while wave 0 polls
      if (tid < 64) {
        const unsigned* f = bar + (bb * 64 + tid) * 16;
        // bounded spin: a protocol bug fails verification instead of hanging
        for (int spin = 0; spin < (1 << 20); ++spin) {
          if (AG_LOAD(f) >= (unsigned)t) break;
          __builtin_amdgcn_s_sleep(1);
        }
      }
      __syncthreads();
      __builtin_amdgcn_sched_barrier(0);  // pin: no h-load hoist above the poll
    }
  }
}

// ---------------------------------------------------------------------------
extern "C" void kernel_launch(void* const* d_in, const int* in_sizes, int n_in,
                              void* d_out, int out_size, void* d_ws, size_t ws_size,
                              hipStream_t stream) {
  (void)in_sizes; (void)n_in; (void)out_size; (void)ws_size;
  const float* dh   = (const float*)d_in[0];
  // d_in[1] ("outputs") is unused by the reference
  const int*   caps = (const int*)d_in[2];
  const float* W_ih = (const float*)d_in[3];
  const float* W_hh = (const float*)d_in[4];
  const float* b_ih = (const float*)d_in[5];
  const float* b_hh = (const float*)d_in[6];
  float* out = (float*)d_out;

  // Workspace layout (~282.1 MB):
  char* ws = (char*)d_ws;
  _Float16* Wx116 = (_Float16*)(ws);                 //   8,388,608
  _Float16* Wfrag = (_Float16*)(ws + 8388608);       //   8,388,608 (fragment-ordered Whh)
  _Float16* Wp    = (_Float16*)(ws + 16777216);      //   8,388,608
  _Float16* dh16  = (_Float16*)(ws + 25165824);      //  50,331,648 (REUSED as h slabs after gemm_x)
  _Float16* pld16 = (_Float16*)(ws + 75497472);      //   1,048,576
  float*    Xc    = (float*)   (ws + 76546048);      //   8,388,608
  _Float16* Xall  = (_Float16*)(ws + 84934656);      // 197,132,288 (47*512*4096 f16)
  unsigned* bar   = (unsigned*)(ws + 282066944);     //  16,384 B flag region

  prep_w<<<32768, 256, 0, stream>>>(W_ih, Wx116, Wp);
  prep_wfrag<<<2048, 256, 0, stream>>>(W_hh, Wfrag);
  pool_conv<<<2048, 256, 0, stream>>>(dh, caps, dh16, pld16);
  init_zero<<<2048, 256, 0, stream>>>(out, bar);
  gemm_pool<<<dim3(32, 8), 256, 0, stream>>>(pld16, Wp, b_ih, b_hh, Xc);
  // A = dh16 rows from t=1 onward: dh16 + 512*1024 elements, [24064 x 1024] f16
  gemm_x<<<dim3(32, 188), 256, 0, stream>>>(dh16 + 524288, Wx116, Xc, Xall);
  // h slab t (t=1..47) lives at dh16-region byte offset t*1MB (dh16 dead after gemm_x)
  lstm_all<<<256, 256, 0, stream>>>(Wfrag, Xall, dh16, out, bar);
}

// Round 8
// 1107.656 us; speedup vs baseline: 1.8828x; 1.0742x over previous
//
#include <hip/hip_runtime.h>
#include <math.h>
#include <stdint.h>

// Problem constants
#define B_ 512
#define D_ 1024
#define H_ 1024
#define T_ 48
#define NG 4096      // 4*H gate columns

typedef _Float16 half8 __attribute__((ext_vector_type(8)));
typedef float f32x4 __attribute__((ext_vector_type(4)));

// Agent-scope (device-coherent) helpers — compiler-generated ops only.
#define AG_LOAD(p)      __hip_atomic_load((p), __ATOMIC_RELAXED, __HIP_MEMORY_SCOPE_AGENT)
#define AG_STORE(p, v)  __hip_atomic_store((p), (v), __ATOMIC_RELAXED, __HIP_MEMORY_SCOPE_AGENT)

// Async global->LDS, 16B per lane. LDS dest must be wave-uniform base; HW adds lane*16.
__device__ __forceinline__ void cp16(const void* g, void* l) {
  __builtin_amdgcn_global_load_lds(
      (__attribute__((address_space(1))) const unsigned int*)(uintptr_t)g,
      (__attribute__((address_space(3))) unsigned int*)(uintptr_t)l, 16, 0, 0);
}

__device__ __forceinline__ float sigmoidf_(float x) { return 1.0f / (1.0f + expf(-x)); }

// Fast gate math (lstm epilogue only): v_exp_f32 + v_rcp_f32.
// rel err ~1e-6 << 0.0039 budget; stable at extremes (2^y never overflows for
// realistic gate magnitudes; rcp(inf)=0 gives exact saturation).
__device__ __forceinline__ float fast_sig(float x) {
  return __builtin_amdgcn_rcpf(1.0f + __expf(-x));
}
__device__ __forceinline__ float fast_tanh(float x) {
  return 1.0f - 2.0f * __builtin_amdgcn_rcpf(1.0f + __expf(2.0f * x));
}

// ---------------------------------------------------------------------------
// Prep: Wx1[j][k]=W_ih[j][k] (k<1024) f16; Wp[j][k]=W_ih[j][1024+k] f16
// ---------------------------------------------------------------------------
__global__ void prep_w(const float* __restrict__ W_ih,
                       _Float16* __restrict__ Wx1, _Float16* __restrict__ Wp) {
  int idx = blockIdx.x * 256 + threadIdx.x;  // < 8388608
  const int n1 = NG * H_;  // 4,194,304
  if (idx < n1) {
    int j = idx >> 10, k = idx & 1023;
    Wx1[idx] = (_Float16)W_ih[j * 2048 + k];
  } else {
    int i3 = idx - n1;
    int j = i3 >> 10, k = i3 & 1023;
    Wp[i3] = (_Float16)W_ih[j * 2048 + 1024 + k];
  }
}

// ---------------------------------------------------------------------------
// Whh -> MFMA B-fragment order, per column-block cb (16 hidden cols).
// Fragment f = ((cb*4 + n)*32 + kc)*64 + lane holds half8:
//   B[row = n*1024 + cb*16 + (lane&15)][k = kc*32 + (lane>>4)*8 .. +8]
// ---------------------------------------------------------------------------
__global__ void prep_wfrag(const float* __restrict__ W_hh, _Float16* __restrict__ Wf) {
  int f = blockIdx.x * 256 + threadIdx.x;  // < 524288
  int cb = f >> 13;
  int rem = f & 8191;
  int n = rem >> 11;
  int kc = (rem >> 6) & 31;
  int lane = rem & 63;
  int l16 = lane & 15, quad = lane >> 4;
  const float* s = W_hh + (size_t)(n * 1024 + cb * 16 + l16) * 1024 + kc * 32 + quad * 8;
  half8 v;
#pragma unroll
  for (int i = 0; i < 8; ++i) v[i] = (_Float16)s[i];
  *(half8*)(Wf + (size_t)f * 8) = v;
}

// ---------------------------------------------------------------------------
// Pool: pooled[b][d] = sum_t mask(t,b)*dh[t][b][d] / sum_t mask(t,b); also dh->f16 (t>=1)
// ---------------------------------------------------------------------------
__global__ void pool_conv(const float* __restrict__ dh, const int* __restrict__ caps,
                          _Float16* __restrict__ dh16, _Float16* __restrict__ pooled16) {
  int tid = blockIdx.x * 256 + threadIdx.x;  // b*1024 + d, < 524288
  int b = tid >> 10;
  float sum = 0.0f, cnt = 0.0f;
  for (int t = 0; t < T_; ++t) {
    int cap = caps[t * B_ + b];
    float v = dh[(size_t)t * (B_ * D_) + tid];
    if (cap != 0 && cap != 2) { sum += v; cnt += 1.0f; }
    if (t >= 1) dh16[(size_t)t * (B_ * D_) + tid] = (_Float16)v;
  }
  pooled16[tid] = (_Float16)(sum / cnt);
}

// ---------------------------------------------------------------------------
// Init: feats[:,0,:]=0, barrier flags = 0 (AGENT-scope; at the coherence point
// before lstm_all's agent-scope polls read them).
// ---------------------------------------------------------------------------
__global__ void init_zero(float* __restrict__ out, unsigned* __restrict__ bar) {
  int tid = blockIdx.x * 256 + threadIdx.x;  // < 524288
  int b = tid >> 10, d = tid & 1023;
  out[(size_t)b * (T_ * H_) + d] = 0.0f;
  if (tid < 4096) AG_STORE(&bar[tid], 0u);
}

// ---------------------------------------------------------------------------
// Xc[b][n] = sum_k pooled[b][k]*Wp[n][k] + b_ih[n] + b_hh[n]   (f32, B x 4096)
// ---------------------------------------------------------------------------
__global__ __launch_bounds__(256) void gemm_pool(
    const _Float16* __restrict__ A, const _Float16* __restrict__ Wp,
    const float* __restrict__ b_ih, const float* __restrict__ b_hh,
    float* __restrict__ Xc) {
  __shared__ __align__(16) _Float16 sA[64 * 32];
  __shared__ __align__(16) _Float16 sB[128 * 32];
  const int tid = threadIdx.x;
  const int wave = tid >> 6, lane = tid & 63;
  const int quad = lane >> 4, l16 = lane & 15;
  const int wm = wave & 1, wn = wave >> 1;
  const int n0 = blockIdx.x * 128;
  const int b0 = blockIdx.y * 64;
  const int rS = tid >> 2, cS = tid & 3;

  f32x4 acc[2][4] = {};
  for (int k0 = 0; k0 < 1024; k0 += 32) {
    cp16(A + (size_t)(b0 + rS) * 1024 + k0 + cS * 8, sA + wave * 512);
    cp16(Wp + (size_t)(n0 + rS) * 1024 + k0 + cS * 8, sB + wave * 512);
    cp16(Wp + (size_t)(n0 + 64 + rS) * 1024 + k0 + cS * 8, sB + 2048 + wave * 512);
    __syncthreads();
    half8 a[2], bfr[4];
#pragma unroll
    for (int m = 0; m < 2; ++m)
      a[m] = *(const half8*)(sA + (wm * 32 + m * 16 + l16) * 32 + quad * 8);
#pragma unroll
    for (int n = 0; n < 4; ++n)
      bfr[n] = *(const half8*)(sB + (wn * 64 + n * 16 + l16) * 32 + quad * 8);
#pragma unroll
    for (int m = 0; m < 2; ++m)
#pragma unroll
      for (int n = 0; n < 4; ++n)
        acc[m][n] = __builtin_amdgcn_mfma_f32_16x16x32_f16(a[m], bfr[n], acc[m][n], 0, 0, 0);
    __syncthreads();
  }
#pragma unroll
  for (int m = 0; m < 2; ++m) {
#pragma unroll
    for (int n = 0; n < 4; ++n) {
      int nn = n0 + wn * 64 + n * 16 + l16;
      float bias = b_ih[nn] + b_hh[nn];
#pragma unroll
      for (int r = 0; r < 4; ++r) {
        int bb = b0 + wm * 32 + m * 16 + quad * 4 + r;
        Xc[(size_t)bb * NG + nn] = acc[m][n][r] + bias;
      }
    }
  }
}

// ---------------------------------------------------------------------------
// Big input-projection GEMM: Xall[r][n] (f16) = sum_k A[r][k]*Wx1[n][k] + Xc[r&511][n]
// M=24064, N=4096, K=1024. 128x128 tile, 2-phase double-buffered LDS.
// Verified round-2 version, unchanged.
// ---------------------------------------------------------------------------
__global__ __launch_bounds__(256) void gemm_x(
    const _Float16* __restrict__ A, const _Float16* __restrict__ Bw,
    const float* __restrict__ Xc, _Float16* __restrict__ Xall) {
  __shared__ __align__(16) _Float16 sA[2][128 * 32];
  __shared__ __align__(16) _Float16 sB[2][128 * 32];
  const int tid = threadIdx.x;
  const int wave = tid >> 6, lane = tid & 63;
  const int quad = lane >> 4, l16 = lane & 15;
  const int wm = wave & 1, wn = wave >> 1;
  const int n0 = blockIdx.x * 128;
  const int m0 = blockIdx.y * 128;
  const int rS = tid >> 2, cS = tid & 3;

  const _Float16* aR0 = A + (size_t)(m0 + rS) * 1024 + cS * 8;
  const _Float16* aR1 = A + (size_t)(m0 + 64 + rS) * 1024 + cS * 8;
  const _Float16* bR0 = Bw + (size_t)(n0 + rS) * 1024 + cS * 8;
  const _Float16* bR1 = Bw + (size_t)(n0 + 64 + rS) * 1024 + cS * 8;

  f32x4 acc[4][4] = {};

  auto stage = [&](int buf, int k0) {
    cp16(aR0 + k0, &sA[buf][wave * 512]);
    cp16(aR1 + k0, &sA[buf][2048 + wave * 512]);
    cp16(bR0 + k0, &sB[buf][wave * 512]);
    cp16(bR1 + k0, &sB[buf][2048 + wave * 512]);
  };
  auto compute = [&](int cur) {
    half8 a[4], b[4];
#pragma unroll
    for (int m = 0; m < 4; ++m)
      a[m] = *(const half8*)&sA[cur][(wm * 64 + m * 16 + l16) * 32 + quad * 8];
#pragma unroll
    for (int n = 0; n < 4; ++n)
      b[n] = *(const half8*)&sB[cur][(wn * 64 + n * 16 + l16) * 32 + quad * 8];
#pragma unroll
    for (int m = 0; m < 4; ++m)
#pragma unroll
      for (int n = 0; n < 4; ++n)
        acc[m][n] = __builtin_amdgcn_mfma_f32_16x16x32_f16(a[m], b[n], acc[m][n], 0, 0, 0);
  };

  stage(0, 0);
  __syncthreads();
  for (int it = 0; it < 31; ++it) {
    const int cur = it & 1;
    stage(cur ^ 1, (it + 1) * 32);
    compute(cur);
    __syncthreads();
  }
  compute(1);  // it=31

#pragma unroll
  for (int m = 0; m < 4; ++m) {
#pragma unroll
    for (int n = 0; n < 4; ++n) {
      const int col = n0 + wn * 64 + n * 16 + l16;
#pragma unroll
      for (int r = 0; r < 4; ++r) {
        const int row = m0 + wm * 64 + m * 16 + quad * 4 + r;
        Xall[(size_t)row * NG + col] =
            (_Float16)(acc[m][n][r] + Xc[(size_t)(row & 511) * NG + col]);
      }
    }
  }
}

// ---------------------------------------------------------------------------
// PERSISTENT recurrent kernel. Protocol byte-identical to the passing r6/r7
// version. Round-8 changes (both local to this kernel):
//  (1) epilogue gate math via fast_sig/fast_tanh (v_exp+v_rcp) — the precise
//      expf/tanhf expansions were ~2+ us/step of serial VALU (VALUBusy 17.7%);
//  (2) h lookahead deepened 4 -> 6 slots (+32 VGPR, 1 block/CU unaffected) —
//      covers ~840cy of the ~900cy IF$ first-touch latency (was ~560cy).
// ---------------------------------------------------------------------------
__global__ __launch_bounds__(256, 1) void lstm_all(
    const _Float16* __restrict__ Wf, const _Float16* __restrict__ Xall,
    _Float16* __restrict__ hs, float* __restrict__ out,
    unsigned* __restrict__ bar) {
  __shared__ __align__(16) _Float16 wlds[65536];  // 128 KiB
  const int tid = threadIdx.x;
  const int wave = tid >> 6, lane = tid & 63;
  const int quad = lane >> 4, l16 = lane & 15;
  const int cb = blockIdx.x >> 2, bb = blockIdx.x & 3;
  const int col = cb * 16 + l16;

  // --- weight fragments -> LDS, once (fully coalesced, linear dest)
  {
    const _Float16* src = Wf + (size_t)cb * 65536;
#pragma unroll
    for (int i = 0; i < 32; ++i)
      cp16(src + (size_t)(i * 256 + wave * 64 + lane) * 8,
           wlds + (i * 256 + wave * 64) * 8);
  }
  __syncthreads();

  float cc[2][4] = {{0.f, 0.f, 0.f, 0.f}, {0.f, 0.f, 0.f, 0.f}};

  // Xall prefetch registers (filled for step t before its iteration begins)
  _Float16 xh[2][4][4];
  auto prefetchX = [&](int t) {
    const _Float16* xb =
        Xall + ((size_t)(t - 1) * 512 + bb * 128 + wave * 32) * NG + col;
#pragma unroll
    for (int m = 0; m < 2; ++m)
#pragma unroll
      for (int r = 0; r < 4; ++r) {
        const _Float16* xr = xb + (size_t)(m * 16 + quad * 4 + r) * NG;
#pragma unroll
        for (int n = 0; n < 4; ++n) xh[m][n][r] = xr[n * 1024];
      }
  };
  prefetchX(1);

  for (int t = 1; t < T_; ++t) {
    f32x4 acc[2][4] = {};
    if (t > 1) {
      const _Float16* hp = hs + (size_t)(t - 1) * 524288;
      const _Float16* aB0 = hp + (size_t)(bb * 128 + wave * 32 + l16) * 1024 + quad * 8;
      const _Float16* aB1 = aB0 + 16 * 1024;
      half8 abuf[6][2][2];  // [slot][m][kk] — all indices compile-time (full unroll)
#define LOADA(P, CH)                                      \
  do {                                                    \
    abuf[P][0][0] = *(const half8*)(aB0 + (CH) * 64);      \
    abuf[P][0][1] = *(const half8*)(aB0 + (CH) * 64 + 32); \
    abuf[P][1][0] = *(const half8*)(aB1 + (CH) * 64);      \
    abuf[P][1][1] = *(const half8*)(aB1 + (CH) * 64 + 32); \
  } while (0)
      LOADA(0, 0);
      LOADA(1, 1);
      LOADA(2, 2);
      LOADA(3, 3);
      LOADA(4, 4);
      LOADA(5, 5);
#pragma unroll
      for (int ch = 0; ch < 16; ++ch) {
        half8 bf[2][4];
#pragma unroll
        for (int kk = 0; kk < 2; ++kk)
#pragma unroll
          for (int n = 0; n < 4; ++n)
            bf[kk][n] =
                *(const half8*)&wlds[(size_t)((n * 32 + ch * 2 + kk) * 64 + lane) * 8];
        const int p = ch % 6;
#pragma unroll
        for (int kk = 0; kk < 2; ++kk)
#pragma unroll
          for (int m = 0; m < 2; ++m)
#pragma unroll
            for (int n = 0; n < 4; ++n)
              acc[m][n] = __builtin_amdgcn_mfma_f32_16x16x32_f16(
                  abuf[p][m][kk], bf[kk][n], acc[m][n], 0, 0, 0);
        if (ch < 10) LOADA(p, ch + 6);
      }
#undef LOADA
    }

    // --- epilogue: gates -> c (regs) -> h slab t (agent-coherent) + out
    _Float16* hw = hs + (size_t)t * 524288;
#pragma unroll
    for (int m = 0; m < 2; ++m)
#pragma unroll
      for (int r = 0; r < 4; ++r) {
        int b = bb * 128 + wave * 32 + m * 16 + quad * 4 + r;
        float iv = acc[m][0][r] + (float)xh[m][0][r];
        float fv = acc[m][1][r] + (float)xh[m][1][r];
        float gv = acc[m][2][r] + (float)xh[m][2][r];
        float ov = acc[m][3][r] + (float)xh[m][3][r];
        float ig = fast_sig(iv), fg = fast_sig(fv), og = fast_sig(ov);
        float gg = fast_tanh(gv);
        float cn = fg * cc[m][r] + ig * gg;
        cc[m][r] = cn;
        float hv = og * fast_tanh(cn);
        _Float16 hv16 = (_Float16)hv;
        AG_STORE((unsigned short*)(hw + (size_t)b * 1024 + col),
                 __builtin_bit_cast(unsigned short, hv16));
        out[(size_t)b * (T_ * H_) + (size_t)t * H_ + col] = hv;
      }

    if (t + 1 < T_) {
      __syncthreads();  // compiler-emitted vmcnt(0) drain: h stores at coherence pt
      if (tid == 0)
        AG_STORE(&bar[(bb * 64 + cb) * 16], (unsigned)t);
      prefetchX(t + 1);  // drains while wave 0 polls
      if (tid < 64) {
        const unsigned* f = bar + (bb * 64 + tid) * 16;
        // bounded spin: a protocol bug fails verification instead of hanging
        for (int spin = 0; spin < (1 << 20); ++spin) {
          if (AG_LOAD(f) >= (unsigned)t) break;
          __builtin_amdgcn_s_sleep(1);
        }
      }
      __syncthreads();
      __builtin_amdgcn_sched_barrier(0);  // pin: no h-load hoist above the poll
    }
  }
}

// ---------------------------------------------------------------------------
extern "C" void kernel_launch(void* const* d_in, const int* in_sizes, int n_in,
                              void* d_out, int out_size, void* d_ws, size_t ws_size,
                              hipStream_t stream) {
  (void)in_sizes; (void)n_in; (void)out_size; (void)ws_size;
  const float* dh   = (const float*)d_in[0];
  // d_in[1] ("outputs") is unused by the reference
  const int*   caps = (const int*)d_in[2];
  const float* W_ih = (const float*)d_in[3];
  const float* W_hh = (const float*)d_in[4];
  const float* b_ih = (const float*)d_in[5];
  const float* b_hh = (const float*)d_in[6];
  float* out = (float*)d_out;

  // Workspace layout (~282.1 MB):
  char* ws = (char*)d_ws;
  _Float16* Wx116 = (_Float16*)(ws);                 //   8,388,608
  _Float16* Wfrag = (_Float16*)(ws + 8388608);       //   8,388,608 (fragment-ordered Whh)
  _Float16* Wp    = (_Float16*)(ws + 16777216);      //   8,388,608
  _Float16* dh16  = (_Float16*)(ws + 25165824);      //  50,331,648 (REUSED as h slabs after gemm_x)
  _Float16* pld16 = (_Float16*)(ws + 75497472);      //   1,048,576
  float*    Xc    = (float*)   (ws + 76546048);      //   8,388,608
  _Float16* Xall  = (_Float16*)(ws + 84934656);      // 197,132,288 (47*512*4096 f16)
  unsigned* bar   = (unsigned*)(ws + 282066944);     //  16,384 B flag region

  prep_w<<<32768, 256, 0, stream>>>(W_ih, Wx116, Wp);
  prep_wfrag<<<2048, 256, 0, stream>>>(W_hh, Wfrag);
  pool_conv<<<2048, 256, 0, stream>>>(dh, caps, dh16, pld16);
  init_zero<<<2048, 256, 0, stream>>>(out, bar);
  gemm_pool<<<dim3(32, 8), 256, 0, stream>>>(pld16, Wp, b_ih, b_hh, Xc);
  // A = dh16 rows from t=1 onward: dh16 + 512*1024 elements, [24064 x 1024] f16
  gemm_x<<<dim3(32, 188), 256, 0, stream>>>(dh16 + 524288, Wx116, Xc, Xall);
  // h slab t (t=1..47) lives at dh16-region byte offset t*1MB (dh16 dead after gemm_x)
  lstm_all<<<256, 256, 0, stream>>>(Wfrag, Xall, dh16, out, bar);
}

// Round 10
// 1041.561 us; speedup vs baseline: 2.0023x; 1.0635x over previous
//
#include <hip/hip_runtime.h>
#include <math.h>
#include <stdint.h>

// Problem constants
#define B_ 512
#define D_ 1024
#define H_ 1024
#define T_ 48
#define NG 4096      // 4*H gate columns

typedef _Float16 half8 __attribute__((ext_vector_type(8)));
typedef float f32x4 __attribute__((ext_vector_type(4)));

// Agent-scope (device-coherent) helpers — compiler-generated ops only.
#define AG_LOAD(p)      __hip_atomic_load((p), __ATOMIC_RELAXED, __HIP_MEMORY_SCOPE_AGENT)
#define AG_STORE(p, v)  __hip_atomic_store((p), (v), __ATOMIC_RELAXED, __HIP_MEMORY_SCOPE_AGENT)

// Async global->LDS, 16B per lane. LDS dest must be wave-uniform base; HW adds lane*16.
__device__ __forceinline__ void cp16(const void* g, void* l) {
  __builtin_amdgcn_global_load_lds(
      (__attribute__((address_space(1))) const unsigned int*)(uintptr_t)g,
      (__attribute__((address_space(3))) unsigned int*)(uintptr_t)l, 16, 0, 0);
}

__device__ __forceinline__ float sigmoidf_(float x) { return 1.0f / (1.0f + expf(-x)); }

// Fast gate math (lstm epilogue only): v_exp_f32 + v_rcp_f32.
__device__ __forceinline__ float fast_sig(float x) {
  return __builtin_amdgcn_rcpf(1.0f + __expf(-x));
}
__device__ __forceinline__ float fast_tanh(float x) {
  return 1.0f - 2.0f * __builtin_amdgcn_rcpf(1.0f + __expf(2.0f * x));
}

// ---------------------------------------------------------------------------
// Prep: Wx1[j][k]=W_ih[j][k] (k<1024) f16; Wp[j][k]=W_ih[j][1024+k] f16
// ---------------------------------------------------------------------------
__global__ void prep_w(const float* __restrict__ W_ih,
                       _Float16* __restrict__ Wx1, _Float16* __restrict__ Wp) {
  int idx = blockIdx.x * 256 + threadIdx.x;  // < 8388608
  const int n1 = NG * H_;  // 4,194,304
  if (idx < n1) {
    int j = idx >> 10, k = idx & 1023;
    Wx1[idx] = (_Float16)W_ih[j * 2048 + k];
  } else {
    int i3 = idx - n1;
    int j = i3 >> 10, k = i3 & 1023;
    Wp[i3] = (_Float16)W_ih[j * 2048 + 1024 + k];
  }
}

// ---------------------------------------------------------------------------
// Whh -> MFMA B-fragment order, per column-block cb (16 hidden cols).
// Fragment f = ((cb*4 + n)*32 + kc)*64 + lane holds half8:
//   B[row = n*1024 + cb*16 + (lane&15)][k = kc*32 + (lane>>4)*8 .. +8]
// ---------------------------------------------------------------------------
__global__ void prep_wfrag(const float* __restrict__ W_hh, _Float16* __restrict__ Wf) {
  int f = blockIdx.x * 256 + threadIdx.x;  // < 524288
  int cb = f >> 13;
  int rem = f & 8191;
  int n = rem >> 11;
  int kc = (rem >> 6) & 31;
  int lane = rem & 63;
  int l16 = lane & 15, quad = lane >> 4;
  const float* s = W_hh + (size_t)(n * 1024 + cb * 16 + l16) * 1024 + kc * 32 + quad * 8;
  half8 v;
#pragma unroll
  for (int i = 0; i < 8; ++i) v[i] = (_Float16)s[i];
  *(half8*)(Wf + (size_t)f * 8) = v;
}

// ---------------------------------------------------------------------------
// Pool: pooled[b][d] = sum_t mask(t,b)*dh[t][b][d] / sum_t mask(t,b); also dh->f16 (t>=1)
// ---------------------------------------------------------------------------
__global__ void pool_conv(const float* __restrict__ dh, const int* __restrict__ caps,
                          _Float16* __restrict__ dh16, _Float16* __restrict__ pooled16) {
  int tid = blockIdx.x * 256 + threadIdx.x;  // b*1024 + d, < 524288
  int b = tid >> 10;
  float sum = 0.0f, cnt = 0.0f;
  for (int t = 0; t < T_; ++t) {
    int cap = caps[t * B_ + b];
    float v = dh[(size_t)t * (B_ * D_) + tid];
    if (cap != 0 && cap != 2) { sum += v; cnt += 1.0f; }
    if (t >= 1) dh16[(size_t)t * (B_ * D_) + tid] = (_Float16)v;
  }
  pooled16[tid] = (_Float16)(sum / cnt);
}

// ---------------------------------------------------------------------------
// Init: feats[:,0,:]=0, barrier flags = 0 (AGENT-scope).
// ---------------------------------------------------------------------------
__global__ void init_zero(float* __restrict__ out, unsigned* __restrict__ bar) {
  int tid = blockIdx.x * 256 + threadIdx.x;  // < 524288
  int b = tid >> 10, d = tid & 1023;
  out[(size_t)b * (T_ * H_) + d] = 0.0f;
  if (tid < 4096) AG_STORE(&bar[tid], 0u);
}

// ---------------------------------------------------------------------------
// Xc[b][n] = sum_k pooled[b][k]*Wp[n][k] + b_ih[n] + b_hh[n]   (f32, B x 4096)
// ---------------------------------------------------------------------------
__global__ __launch_bounds__(256) void gemm_pool(
    const _Float16* __restrict__ A, const _Float16* __restrict__ Wp,
    const float* __restrict__ b_ih, const float* __restrict__ b_hh,
    float* __restrict__ Xc) {
  __shared__ __align__(16) _Float16 sA[64 * 32];
  __shared__ __align__(16) _Float16 sB[128 * 32];
  const int tid = threadIdx.x;
  const int wave = tid >> 6, lane = tid & 63;
  const int quad = lane >> 4, l16 = lane & 15;
  const int wm = wave & 1, wn = wave >> 1;
  const int n0 = blockIdx.x * 128;
  const int b0 = blockIdx.y * 64;
  const int rS = tid >> 2, cS = tid & 3;

  f32x4 acc[2][4] = {};
  for (int k0 = 0; k0 < 1024; k0 += 32) {
    cp16(A + (size_t)(b0 + rS) * 1024 + k0 + cS * 8, sA + wave * 512);
    cp16(Wp + (size_t)(n0 + rS) * 1024 + k0 + cS * 8, sB + wave * 512);
    cp16(Wp + (size_t)(n0 + 64 + rS) * 1024 + k0 + cS * 8, sB + 2048 + wave * 512);
    __syncthreads();
    half8 a[2], bfr[4];
#pragma unroll
    for (int m = 0; m < 2; ++m)
      a[m] = *(const half8*)(sA + (wm * 32 + m * 16 + l16) * 32 + quad * 8);
#pragma unroll
    for (int n = 0; n < 4; ++n)
      bfr[n] = *(const half8*)(sB + (wn * 64 + n * 16 + l16) * 32 + quad * 8);
#pragma unroll
    for (int m = 0; m < 2; ++m)
#pragma unroll
      for (int n = 0; n < 4; ++n)
        acc[m][n] = __builtin_amdgcn_mfma_f32_16x16x32_f16(a[m], bfr[n], acc[m][n], 0, 0, 0);
    __syncthreads();
  }
#pragma unroll
  for (int m = 0; m < 2; ++m) {
#pragma unroll
    for (int n = 0; n < 4; ++n) {
      int nn = n0 + wn * 64 + n * 16 + l16;
      float bias = b_ih[nn] + b_hh[nn];
#pragma unroll
      for (int r = 0; r < 4; ++r) {
        int bb = b0 + wm * 32 + m * 16 + quad * 4 + r;
        Xc[(size_t)bb * NG + nn] = acc[m][n][r] + bias;
      }
    }
  }
}

// ---------------------------------------------------------------------------
// Big input-projection GEMM: Xall[r][n] (f16) = sum_k A[r][k]*Wx1[n][k] + Xc[r&511][n]
// M=24064, N=4096, K=1024. 128x128 tile, 2-phase double-buffered LDS.
// Verified round-2 version, unchanged.
// ---------------------------------------------------------------------------
__global__ __launch_bounds__(256) void gemm_x(
    const _Float16* __restrict__ A, const _Float16* __restrict__ Bw,
    const float* __restrict__ Xc, _Float16* __restrict__ Xall) {
  __shared__ __align__(16) _Float16 sA[2][128 * 32];
  __shared__ __align__(16) _Float16 sB[2][128 * 32];
  const int tid = threadIdx.x;
  const int wave = tid >> 6, lane = tid & 63;
  const int quad = lane >> 4, l16 = lane & 15;
  const int wm = wave & 1, wn = wave >> 1;
  const int n0 = blockIdx.x * 128;
  const int m0 = blockIdx.y * 128;
  const int rS = tid >> 2, cS = tid & 3;

  const _Float16* aR0 = A + (size_t)(m0 + rS) * 1024 + cS * 8;
  const _Float16* aR1 = A + (size_t)(m0 + 64 + rS) * 1024 + cS * 8;
  const _Float16* bR0 = Bw + (size_t)(n0 + rS) * 1024 + cS * 8;
  const _Float16* bR1 = Bw + (size_t)(n0 + 64 + rS) * 1024 + cS * 8;

  f32x4 acc[4][4] = {};

  auto stage = [&](int buf, int k0) {
    cp16(aR0 + k0, &sA[buf][wave * 512]);
    cp16(aR1 + k0, &sA[buf][2048 + wave * 512]);
    cp16(bR0 + k0, &sB[buf][wave * 512]);
    cp16(bR1 + k0, &sB[buf][2048 + wave * 512]);
  };
  auto compute = [&](int cur) {
    half8 a[4], b[4];
#pragma unroll
    for (int m = 0; m < 4; ++m)
      a[m] = *(const half8*)&sA[cur][(wm * 64 + m * 16 + l16) * 32 + quad * 8];
#pragma unroll
    for (int n = 0; n < 4; ++n)
      b[n] = *(const half8*)&sB[cur][(wn * 64 + n * 16 + l16) * 32 + quad * 8];
#pragma unroll
    for (int m = 0; m < 4; ++m)
#pragma unroll
      for (int n = 0; n < 4; ++n)
        acc[m][n] = __builtin_amdgcn_mfma_f32_16x16x32_f16(a[m], b[n], acc[m][n], 0, 0, 0);
  };

  stage(0, 0);
  __syncthreads();
  for (int it = 0; it < 31; ++it) {
    const int cur = it & 1;
    stage(cur ^ 1, (it + 1) * 32);
    compute(cur);
    __syncthreads();
  }
  compute(1);  // it=31

#pragma unroll
  for (int m = 0; m < 4; ++m) {
#pragma unroll
    for (int n = 0; n < 4; ++n) {
      const int col = n0 + wn * 64 + n * 16 + l16;
#pragma unroll
      for (int r = 0; r < 4; ++r) {
        const int row = m0 + wm * 64 + m * 16 + quad * 4 + r;
        Xall[(size_t)row * NG + col] =
            (_Float16)(acc[m][n][r] + Xc[(size_t)(row & 511) * NG + col]);
      }
    }
  }
}

// ---------------------------------------------------------------------------
// PERSISTENT recurrent kernel, round-10: K-split with GLOBAL-scratch exchange.
// 512 threads = 2 wave-groups of 4 waves (2 waves/SIMD). Group g computes
// K in [512g, 512g+512) = 8 chunks (serial h-load chain halved; 6-slot
// lookahead covers 6/8). LDS stays at the PROVEN 131072 B (weights only) —
// round-9's novel 147.8 KB LDS is the prime suspect for its container failure.
// Partial exchange: each block has a private 32 KB scratch in the dead Wp
// region. Same block = same CU = same L1/L2 -> plain stores + __syncthreads
// (vmcnt drain) + plain loads are coherent. Symmetric ownership: group 0
// epilogues batches 0-63 (waves wl 0,1), group 1 batches 64-127 (wl 2,3);
// the non-owner wave with the same wl sends its acc.
// Flag protocol byte-identical to the passing r6/r7/r8 code.
// ---------------------------------------------------------------------------
__global__ __launch_bounds__(512, 2) void lstm_all(
    const _Float16* __restrict__ Wf, const _Float16* __restrict__ Xall,
    _Float16* __restrict__ hs, float* __restrict__ out,
    unsigned* __restrict__ bar, float* __restrict__ xch) {
  __shared__ __align__(16) _Float16 wlds[65536];  // 128 KiB (proven size)
  const int tid = threadIdx.x;
  const int wave = tid >> 6, lane = tid & 63;
  const int grp = wave >> 2;        // K-split group 0/1
  const int wl = wave & 3;          // wave within group
  const int quad = lane >> 4, l16 = lane & 15;
  const int cb = blockIdx.x >> 2, bb = blockIdx.x & 3;
  const int col = cb * 16 + l16;
  const int kb = grp * 8;           // my chunk base (chunk = 64 K-elems)
  // epilogue owner: grp0 owns batches 0-63 (wl 0,1); grp1 owns 64-127 (wl 2,3)
  const bool owner = (grp == 0) ? (wl < 2) : (wl >= 2);
  float* xch_b = xch + (size_t)blockIdx.x * 8192;  // 32 KB private scratch

  // --- weight fragments -> LDS, once (8 waves, fully coalesced, linear dest)
  {
    const _Float16* src = Wf + (size_t)cb * 65536;
#pragma unroll
    for (int i = 0; i < 16; ++i)
      cp16(src + (size_t)((i * 8 + wave) * 64 + lane) * 8,
           wlds + ((i * 8 + wave) * 64) * 8);
  }
  __syncthreads();

  float cc[2][4] = {{0.f, 0.f, 0.f, 0.f}, {0.f, 0.f, 0.f, 0.f}};

  // Xall prefetch registers (owner waves only — consumed by the epilogue)
  _Float16 xh[2][4][4];
  auto prefetchX = [&](int t) {
    const _Float16* xb =
        Xall + ((size_t)(t - 1) * 512 + bb * 128 + wl * 32) * NG + col;
#pragma unroll
    for (int m = 0; m < 2; ++m)
#pragma unroll
      for (int r = 0; r < 4; ++r) {
        const _Float16* xr = xb + (size_t)(m * 16 + quad * 4 + r) * NG;
#pragma unroll
        for (int n = 0; n < 4; ++n) xh[m][n][r] = xr[n * 1024];
      }
  };
  if (owner) prefetchX(1);

  for (int t = 1; t < T_; ++t) {
    f32x4 acc[2][4] = {};
    if (t > 1) {
      const _Float16* hp = hs + (size_t)(t - 1) * 524288;
      const _Float16* aB0 = hp + (size_t)(bb * 128 + wl * 32 + l16) * 1024 + quad * 8;
      const _Float16* aB1 = aB0 + 16 * 1024;
      half8 abuf[6][2][2];  // [slot][m][kk] — all indices compile-time
#define LOADA(P, CH)                                      \
  do {                                                    \
    abuf[P][0][0] = *(const half8*)(aB0 + (CH) * 64);      \
    abuf[P][0][1] = *(const half8*)(aB0 + (CH) * 64 + 32); \
    abuf[P][1][0] = *(const half8*)(aB1 + (CH) * 64);      \
    abuf[P][1][1] = *(const half8*)(aB1 + (CH) * 64 + 32); \
  } while (0)
      LOADA(0, kb + 0);
      LOADA(1, kb + 1);
      LOADA(2, kb + 2);
      LOADA(3, kb + 3);
      LOADA(4, kb + 4);
      LOADA(5, kb + 5);
#pragma unroll
      for (int ch = 0; ch < 8; ++ch) {
        const int cg = kb + ch;  // global chunk for weight fragments
        half8 bf[2][4];
#pragma unroll
        for (int kk = 0; kk < 2; ++kk)
#pragma unroll
          for (int n = 0; n < 4; ++n)
            bf[kk][n] =
                *(const half8*)&wlds[(size_t)((n * 32 + cg * 2 + kk) * 64 + lane) * 8];
        const int p = ch % 6;
#pragma unroll
        for (int kk = 0; kk < 2; ++kk)
#pragma unroll
          for (int m = 0; m < 2; ++m)
#pragma unroll
            for (int n = 0; n < 4; ++n)
              acc[m][n] = __builtin_amdgcn_mfma_f32_16x16x32_f16(
                  abuf[p][m][kk], bf[kk][n], acc[m][n], 0, 0, 0);
        if (ch < 2) LOADA(p, kb + ch + 6);
      }
#undef LOADA
    }

    // --- cross-group exchange through block-private L2 scratch.
    // Non-owner wave (same wl as the owner of its batch range) sends acc;
    // owner adds. Batch-local index bloc = wl*32 + m*16 + quad*4 + r is
    // disjoint across the two senders, so one flat [128][64] f32 array works.
    if (t > 1 && !owner) {
#pragma unroll
      for (int m = 0; m < 2; ++m)
#pragma unroll
        for (int n = 0; n < 4; ++n)
#pragma unroll
          for (int r = 0; r < 4; ++r)
            xch_b[(wl * 32 + m * 16 + quad * 4 + r) * 64 + n * 16 + l16] =
                acc[m][n][r];
    }
    __syncthreads();  // vmcnt(0) drain: sender stores visible (same CU L1/L2)
    if (owner) {
      if (t > 1) {
#pragma unroll
        for (int m = 0; m < 2; ++m)
#pragma unroll
          for (int n = 0; n < 4; ++n)
#pragma unroll
            for (int r = 0; r < 4; ++r)
              acc[m][n][r] +=
                  xch_b[(wl * 32 + m * 16 + quad * 4 + r) * 64 + n * 16 + l16];
      }

      // --- epilogue (owner waves): gates -> c (regs) -> h slab t + out
      _Float16* hw = hs + (size_t)t * 524288;
#pragma unroll
      for (int m = 0; m < 2; ++m)
#pragma unroll
        for (int r = 0; r < 4; ++r) {
          int b = bb * 128 + wl * 32 + m * 16 + quad * 4 + r;
          float iv = acc[m][0][r] + (float)xh[m][0][r];
          float fv = acc[m][1][r] + (float)xh[m][1][r];
          float gv = acc[m][2][r] + (float)xh[m][2][r];
          float ov = acc[m][3][r] + (float)xh[m][3][r];
          float ig = fast_sig(iv), fg = fast_sig(fv), og = fast_sig(ov);
          float gg = fast_tanh(gv);
          float cn = fg * cc[m][r] + ig * gg;
          cc[m][r] = cn;
          float hv = og * fast_tanh(cn);
          _Float16 hv16 = (_Float16)hv;
          AG_STORE((unsigned short*)(hw + (size_t)b * 1024 + col),
                   __builtin_bit_cast(unsigned short, hv16));
          out[(size_t)b * (T_ * H_) + (size_t)t * H_ + col] = hv;
        }
    }

    if (t + 1 < T_) {
      __syncthreads();  // compiler-emitted vmcnt(0) drain: h stores at coherence pt
      if (tid == 0)
        AG_STORE(&bar[(bb * 64 + cb) * 16], (unsigned)t);
      if (owner) prefetchX(t + 1);  // drains while wave 0 polls
      if (tid < 64) {
        const unsigned* f = bar + (bb * 64 + tid) * 16;
        // bounded spin: a protocol bug fails verification instead of hanging
        for (int spin = 0; spin < (1 << 20); ++spin) {
          if (AG_LOAD(f) >= (unsigned)t) break;
          __builtin_amdgcn_s_sleep(1);
        }
      }
      __syncthreads();
      __builtin_amdgcn_sched_barrier(0);  // pin: no h-load hoist above the poll
    }
  }
}

// ---------------------------------------------------------------------------
extern "C" void kernel_launch(void* const* d_in, const int* in_sizes, int n_in,
                              void* d_out, int out_size, void* d_ws, size_t ws_size,
                              hipStream_t stream) {
  (void)in_sizes; (void)n_in; (void)out_size; (void)ws_size;
  const float* dh   = (const float*)d_in[0];
  // d_in[1] ("outputs") is unused by the reference
  const int*   caps = (const int*)d_in[2];
  const float* W_ih = (const float*)d_in[3];
  const float* W_hh = (const float*)d_in[4];
  const float* b_ih = (const float*)d_in[5];
  const float* b_hh = (const float*)d_in[6];
  float* out = (float*)d_out;

  // Workspace layout (~282.1 MB):
  char* ws = (char*)d_ws;
  _Float16* Wx116 = (_Float16*)(ws);                 //   8,388,608
  _Float16* Wfrag = (_Float16*)(ws + 8388608);       //   8,388,608 (fragment-ordered Whh)
  _Float16* Wp    = (_Float16*)(ws + 16777216);      //   8,388,608 (scratch for lstm_all after gemm_pool)
  _Float16* dh16  = (_Float16*)(ws + 25165824);      //  50,331,648 (REUSED as h slabs after gemm_x)
  _Float16* pld16 = (_Float16*)(ws + 75497472);      //   1,048,576
  float*    Xc    = (float*)   (ws + 76546048);      //   8,388,608
  _Float16* Xall  = (_Float16*)(ws + 84934656);      // 197,132,288 (47*512*4096 f16)
  unsigned* bar   = (unsigned*)(ws + 282066944);     //  16,384 B flag region

  prep_w<<<32768, 256, 0, stream>>>(W_ih, Wx116, Wp);
  prep_wfrag<<<2048, 256, 0, stream>>>(W_hh, Wfrag);
  pool_conv<<<2048, 256, 0, stream>>>(dh, caps, dh16, pld16);
  init_zero<<<2048, 256, 0, stream>>>(out, bar);
  gemm_pool<<<dim3(32, 8), 256, 0, stream>>>(pld16, Wp, b_ih, b_hh, Xc);
  // A = dh16 rows from t=1 onward: dh16 + 512*1024 elements, [24064 x 1024] f16
  gemm_x<<<dim3(32, 188), 256, 0, stream>>>(dh16 + 524288, Wx116, Xc, Xall);
  // h slab t (t=1..47) at dh16-region offset t*1MB; Wp region = exchange scratch
  lstm_all<<<256, 512, 0, stream>>>(Wfrag, Xall, dh16, out, bar, (float*)Wp);
}